// Round 8
// baseline (409.322 us; speedup 1.0000x reference)
//
#include <hip/hip_runtime.h>
#include <hip/hip_bf16.h>
#include <math.h>

#define B_   2
#define S_   2048
#define D_   1024
#define H_   16
#define HD_  64
#define DFF_ 4096
#define M_   (B_*S_)   // 4096 rows
#define SCALE_ 0.08838834764831845f  // 1/sqrt(128)

typedef __attribute__((ext_vector_type(8))) short bf16x8;
typedef __attribute__((ext_vector_type(4))) float f32x4;

#define MFMA16(a,b,c) __builtin_amdgcn_mfma_f32_16x16x32_bf16((a),(b),(c),0,0,0)

__device__ __forceinline__ unsigned short f2b(float f) {
    union { float f; unsigned u; } v; v.f = f;
    return (unsigned short)((v.u + 0x7FFFu + ((v.u >> 16) & 1u)) >> 16);
}
__device__ __forceinline__ float b2f(unsigned short s) {
    union { unsigned u; float f; } v; v.u = ((unsigned)s) << 16;
    return v.f;
}
// pack two f32 -> two bf16 (truncating) in ONE v_perm_b32
__device__ __forceinline__ unsigned pk2bf(float a, float b) {
    union { float f; unsigned u; } ua, ub; ua.f = a; ub.f = b;
    return __builtin_amdgcn_perm(ub.u, ua.u, 0x07060302u);
}
__device__ __forceinline__ float softplus_f(float x) {
    return fmaxf(x, 0.f) + log1pf(__expf(-fabsf(x)));
}
// async global->LDS, 16B per lane. LDS dest = base + lane*16 (wave-uniform base).
__device__ __forceinline__ void g2l16(const void* g, void* l) {
    __builtin_amdgcn_global_load_lds(
        (const __attribute__((address_space(1))) unsigned int*)g,
        (__attribute__((address_space(3))) unsigned int*)l, 16, 0, 0);
}

// ---------------------------------------------------------------------------
// Fused prep: ONE launch for x->bf16 conv (+bias concat), the 4 square
// weight transposes, W1T and W2T. All independent; block ranges:
//   [0,4096)       conv (+bqkv build in blocks 0..11)
//   [4096,8192)    wtrans4 (Wq/Wk/Wv/Wo, 1024 blocks each)
//   [8192,12288)   W1T: K=1024, N=4096
//   [12288,16384)  W2T: K=4096, N=1024
// ---------------------------------------------------------------------------
__global__ __launch_bounds__(256) void prep_kernel(
    const float* __restrict__ x, unsigned short* __restrict__ xb,
    const float* __restrict__ bq, const float* __restrict__ bk,
    const float* __restrict__ bv, float* __restrict__ bqkv,
    const float* __restrict__ Wq, const float* __restrict__ Wk,
    const float* __restrict__ Wv, const float* __restrict__ Wo,
    unsigned short* __restrict__ WqkvT, unsigned short* __restrict__ WoT,
    const float* __restrict__ W1, unsigned short* __restrict__ W1T,
    const float* __restrict__ W2, unsigned short* __restrict__ W2T)
{
    __shared__ float tile[32][33];
    const int bid = blockIdx.x;
    const int tid = threadIdx.x;

    if (bid < 4096) {
        // ---- conv + bias concat ----
        int i = (bid * 256 + tid) * 4;
        float4 v = *(const float4*)&x[i];
        ushort4 o;
        o.x = f2b(v.x); o.y = f2b(v.y); o.z = f2b(v.z); o.w = f2b(v.w);
        *(ushort4*)&xb[i] = o;
        int j = bid * 256 + tid;
        if (j < 3072)
            bqkv[j] = (j < 1024) ? bq[j] : (j < 2048 ? bk[j - 1024] : bv[j - 2048]);
        return;
    }

    // ---- transposes: pick source/dest and geometry ----
    const float* W; unsigned short* WT; int K, N, bx, by;
    if (bid < 8192) {
        const int idx = bid - 4096;           // 0..4095
        const int z = idx >> 10;              // 0..3
        W  = (z == 0) ? Wq : (z == 1) ? Wk : (z == 2) ? Wv : Wo;
        WT = (z < 3) ? WqkvT + (size_t)z * 1024 * 1024 : WoT;
        K = 1024; N = 1024;
        bx = idx & 31; by = (idx >> 5) & 31;
    } else if (bid < 12288) {
        const int idx = bid - 8192;           // 0..4095
        W = W1; WT = W1T; K = 1024; N = 4096;
        bx = idx & 127; by = idx >> 7;
    } else {
        const int idx = bid - 12288;          // 0..4095
        W = W2; WT = W2T; K = 4096; N = 1024;
        bx = idx & 31; by = idx >> 5;
    }
    const int n0 = bx * 32, k0 = by * 32;
    const int tx = tid & 31, ty = tid >> 5;   // ty 0..7
    #pragma unroll
    for (int i = 0; i < 4; i++)
        tile[ty + 8*i][tx] = W[(size_t)(k0 + ty + 8*i) * N + n0 + tx];
    __syncthreads();
    #pragma unroll
    for (int i = 0; i < 4; i++)
        WT[(size_t)(n0 + ty + 8*i) * K + k0 + tx] = f2b(tile[tx][ty + 8*i]);
}

// ---------------------------------------------------------------------------
// bf16 GEMM, 128^2 tile, BK=64, XOR-swizzled LDS, double-buffered staging,
// XCD-aware remap, optional split-K. C[M,N]=A[M,lda]@WT[N,lda]^T (+bias z=0).
// R8: optional residual add in epilogue (zz==0): resF fp32 or resB bf16 —
// moves the LN kernels' residual read into the GEMM's compute shadow.
// NOTE (R2 lesson): keep this kernel free of libm calls (sincosf/log1pf) —
// call-clobber forces acc spills -> ~1 GB scratch writeback, 8x slowdown.
// ---------------------------------------------------------------------------
__global__ __launch_bounds__(256) void gemm_bf16_kernel(
    const unsigned short* __restrict__ A,
    const unsigned short* __restrict__ WT,
    const float* __restrict__ bias,
    const float* __restrict__ resF, const unsigned short* __restrict__ resB,
    float* __restrict__ outF, unsigned short* __restrict__ outB,
    int M, int Kslice, int lda, int N, int relu)
{
    __shared__ unsigned short As[2][128 * 64];
    __shared__ unsigned short Bs[2][128 * 64];

    const int tid = threadIdx.x;
    const int w = tid >> 6, lane = tid & 63;
    const int quad = lane >> 4, l16 = lane & 15;

    const int nn = gridDim.x, nm = gridDim.y;
    const int lin = ((int)blockIdx.z * nm + (int)blockIdx.y) * nn + (int)blockIdx.x;
    const int per = (nn * nm * (int)gridDim.z) >> 3;
    const int id  = (lin & 7) * per + (lin >> 3);
    const int zz  = id / (nn * nm);
    const int rem = id - zz * nn * nm;
    const int mt_ = rem / nn, nt_ = rem - mt_ * nn;

    const size_t m0 = (size_t)mt_ * 128, n0 = (size_t)nt_ * 128;
    const int wm = (w >> 1) * 64, wn = (w & 1) * 64;
    const int koff = zz * Kslice;

    const int srow = lane >> 3;                       // 0..7 row within group
    const int sc   = ((lane & 7) ^ srow) * 8;         // swizzled global chunk
    const unsigned short* ga = A  + (m0 + w * 32 + srow) * (size_t)lda + koff + sc;
    const unsigned short* gb = WT + (n0 + w * 32 + srow) * (size_t)lda + koff + sc;
    const size_t rows8 = (size_t)8 * lda;

    f32x4 acc[4][4] = {};
    const int niter = Kslice >> 6;

    #pragma unroll
    for (int j = 0; j < 4; j++) g2l16(ga + j * rows8, &As[0][(w * 32 + j * 8) * 64]);
    #pragma unroll
    for (int j = 0; j < 4; j++) g2l16(gb + j * rows8, &Bs[0][(w * 32 + j * 8) * 64]);

    for (int i = 0; i < niter; i++) {
        __syncthreads();
        if (i + 1 < niter) {
            const int nb = (i + 1) & 1, k0 = (i + 1) << 6;
            #pragma unroll
            for (int j = 0; j < 4; j++)
                g2l16(ga + j * rows8 + k0, &As[nb][(w * 32 + j * 8) * 64]);
            #pragma unroll
            for (int j = 0; j < 4; j++)
                g2l16(gb + j * rows8 + k0, &Bs[nb][(w * 32 + j * 8) * 64]);
        }
        const int buf = i & 1;

        #pragma unroll
        for (int kk = 0; kk < 2; kk++) {
            bf16x8 af[4], bfr[4];
            #pragma unroll
            for (int t = 0; t < 4; t++) {
                const int slot = ((kk * 4 + quad) ^ (l16 & 7)) * 8;
                af[t]  = *(const bf16x8*)&As[buf][(wm + t * 16 + l16) * 64 + slot];
                bfr[t] = *(const bf16x8*)&Bs[buf][(wn + t * 16 + l16) * 64 + slot];
            }
            #pragma unroll
            for (int mt = 0; mt < 4; mt++)
                #pragma unroll
                for (int nt = 0; nt < 4; nt++)
                    acc[mt][nt] = MFMA16(af[mt], bfr[nt], acc[mt][nt]);
        }
    }

    float bv[4];
    #pragma unroll
    for (int nt = 0; nt < 4; nt++)
        bv[nt] = (zz == 0) ? bias[n0 + wn + nt * 16 + l16] : 0.f;

    float* outFz = outF ? outF + (size_t)zz * M * N : nullptr;

    #pragma unroll
    for (int mt = 0; mt < 4; mt++) {
        #pragma unroll
        for (int nt = 0; nt < 4; nt++) {
            const size_t n = n0 + wn + nt * 16 + l16;
            #pragma unroll
            for (int r = 0; r < 4; r++) {
                const size_t m = m0 + wm + mt * 16 + quad * 4 + r;
                float val = acc[mt][nt][r] + bv[nt];
                if (relu) val = fmaxf(val, 0.f);
                const size_t idx = m * N + n;
                if (zz == 0) {
                    if (resF)      val += resF[idx];
                    else if (resB) val += b2f(resB[idx]);
                }
                if (outFz) outFz[idx] = val;
                if (outB) outB[idx] = f2b(val);
            }
        }
    }
}

// ---------------------------------------------------------------------------
// Fused PoPE + V transpose, one launch (both read only qkvb):
//   [0,4096)      PoPE: qkvb -> qp,kp (vectorized ushort4, __sincosf)
//   [4096,5120)   V transpose: qkvb col 2048.. -> vt (B*H, 64, S)
// ---------------------------------------------------------------------------
__global__ __launch_bounds__(256) void popevt_kernel(
    const unsigned short* __restrict__ qkv,
    const float* __restrict__ phase_bias, const float* __restrict__ freqs,
    unsigned short* __restrict__ qp, unsigned short* __restrict__ kp,
    unsigned short* __restrict__ vt)
{
    __shared__ unsigned short tile[64][68];
    const int bid = blockIdx.x;
    const int tid = threadIdx.x;

    if (bid < 4096) {
        // ---- PoPE ----
        int idx = bid * 256 + tid;              // over B*H*S*16
        int d4 = (idx & 15) * 4;
        int s  = (idx >> 4) & (S_ - 1);
        int h  = (idx >> 15) & (H_ - 1);
        int b  = idx >> 19;

        size_t src = (size_t)(b * S_ + s) * 3072 + h * HD_ + d4;
        ushort4 qv = *(const ushort4*)&qkv[src];
        ushort4 kv = *(const ushort4*)&qkv[src + 1024];
        float4 fr = *(const float4*)&freqs[d4];
        float4 pb = *(const float4*)&phase_bias[h * HD_ + d4];
        const float fs = (float)s;

        ushort4 qc4, qs4, kc4, ks4;
        {
            float muq = softplus_f(b2f(qv.x)) * SCALE_, muk = softplus_f(b2f(kv.x));
            float sn, cs; __sincosf(fs * fr.x + pb.x, &sn, &cs);
            qc4.x = f2b(muq * cs); qs4.x = f2b(muq * sn);
            kc4.x = f2b(muk * cs); ks4.x = f2b(muk * sn);
        }
        {
            float muq = softplus_f(b2f(qv.y)) * SCALE_, muk = softplus_f(b2f(kv.y));
            float sn, cs; __sincosf(fs * fr.y + pb.y, &sn, &cs);
            qc4.y = f2b(muq * cs); qs4.y = f2b(muq * sn);
            kc4.y = f2b(muk * cs); ks4.y = f2b(muk * sn);
        }
        {
            float muq = softplus_f(b2f(qv.z)) * SCALE_, muk = softplus_f(b2f(kv.z));
            float sn, cs; __sincosf(fs * fr.z + pb.z, &sn, &cs);
            qc4.z = f2b(muq * cs); qs4.z = f2b(muq * sn);
            kc4.z = f2b(muk * cs); ks4.z = f2b(muk * sn);
        }
        {
            float muq = softplus_f(b2f(qv.w)) * SCALE_, muk = softplus_f(b2f(kv.w));
            float sn, cs; __sincosf(fs * fr.w + pb.w, &sn, &cs);
            qc4.w = f2b(muq * cs); qs4.w = f2b(muq * sn);
            kc4.w = f2b(muk * cs); ks4.w = f2b(muk * sn);
        }

        size_t o = ((size_t)(b * H_ + h) * S_ + s) * 128 + d4;
        *(ushort4*)&qp[o]      = qc4;
        *(ushort4*)&qp[o + 64] = qs4;
        *(ushort4*)&kp[o]      = kc4;
        *(ushort4*)&kp[o + 64] = ks4;
        return;
    }

    // ---- V transpose ----
    const int idx0 = bid - 4096;                 // 0..1023
    const int bh = idx0 >> 5, b = bh >> 4, h = bh & 15;
    const int s0 = (idx0 & 31) * 64;
    #pragma unroll
    for (int i = 0; i < 4; i++) {
        int idx = i * 256 + tid;                 // 64s x 16 d-quads
        int s = idx >> 4, d4 = (idx & 15) * 4;
        *(ushort4*)&tile[s][d4] =
            *(const ushort4*)&qkv[(size_t)(b * S_ + s0 + s) * 3072 + 2048 + h * HD_ + d4];
    }
    __syncthreads();
    #pragma unroll
    for (int i = 0; i < 4; i++) {
        int idx = i * 256 + tid;                 // 64d x 16 s-quads
        int d = idx >> 4, s4 = (idx & 15) * 4;
        ushort4 o;
        o.x = tile[s4][d]; o.y = tile[s4 + 1][d];
        o.z = tile[s4 + 2][d]; o.w = tile[s4 + 3][d];
        *(ushort4*)&vt[((size_t)bh * 64 + d) * S_ + s0 + s4] = o;
    }
}

// ---------------------------------------------------------------------------
// MFMA flash attention: softmax1, lazy normalization, S^T trick,
// 128 q rows/block, dbuf K/V staging, causal split over grid.z.
// R8: wave-uniform dmask branch — interior tiles (majority) skip 32 VALU
// mask ops per kg-loop; diagonal tiles take the masked path. dmask depends
// only on w -> uniform, no divergence. Ledger of failed structural edits:
// setprio (+1.4us), shfl-P-redistr (+9.3us), depth-2 vmcnt (+7.0us).
// ---------------------------------------------------------------------------
__global__ __launch_bounds__(512, 4) void attn_mfma_kernel(
    const unsigned short* __restrict__ qp,
    const unsigned short* __restrict__ kp,
    const unsigned short* __restrict__ vt,
    unsigned short* __restrict__ ao)
{
    __shared__ unsigned short kt_lds[2][64][128];  // [buf][key][k], chunk^=(key&15)
    __shared__ unsigned short vt_lds[2][64][64];   // [buf][d][key], chunk^=(d&7)
    __shared__ unsigned short p_lds[8][16][72];    // per-wave P: [q][key]

    const int tid = threadIdx.x;
    const int w = tid >> 6, lane = tid & 63;
    const int quad = lane >> 4, l16 = lane & 15;
    const int bh = blockIdx.y, b = bh >> 4, h = bh & 15;

    const int a = (blockIdx.z == 0) ? 15 - (int)blockIdx.x : (int)blockIdx.x;
    const int q0b = a * 128;
    const int q0 = q0b + w * 16;

    const unsigned short* qbase = qp + ((size_t)bh * S_ + q0 + l16) * 128 + quad * 8;
    bf16x8 qa[4];
    #pragma unroll
    for (int kc = 0; kc < 4; kc++) qa[kc] = *(const bf16x8*)(qbase + kc * 32);

    const int krow = lane >> 4, kslot = lane & 15;
    const int vrow = lane >> 3, vslot = lane & 7;
    const int kr0 = w * 8 + krow,     kc0 = kslot ^ (kr0 & 15);
    const int kr1 = w * 8 + 4 + krow, kc1 = kslot ^ (kr1 & 15);
    const int vd  = w * 8 + vrow,     vc  = vslot ^ (vd & 7);
    const unsigned short* kg0 = kp + ((size_t)bh * S_ + kr0) * 128 + kc0 * 8;
    const unsigned short* kg1 = kp + ((size_t)bh * S_ + kr1) * 128 + kc1 * 8;
    const unsigned short* vg0 = vt + ((size_t)bh * 64 + vd) * S_ + vc * 8;

    f32x4 o[4] = {};
    float ms = -1e30f, ls = 0.f;

    const int ntiles = 2 * a + 2;

    g2l16(kg0, &kt_lds[0][w * 8][0]);
    g2l16(kg1, &kt_lds[0][w * 8 + 4][0]);
    g2l16(vg0, &vt_lds[0][w * 8][0]);

    for (int ti = 0; ti < ntiles; ti++) {
        const int t0 = ti * 64;
        __syncthreads();
        if (ti + 1 < ntiles) {
            const int nb = (ti + 1) & 1;
            const size_t ko = (size_t)(ti + 1) * (64 * 128);
            const size_t vo = (size_t)(ti + 1) * 64;
            g2l16(kg0 + ko, &kt_lds[nb][w * 8][0]);
            g2l16(kg1 + ko, &kt_lds[nb][w * 8 + 4][0]);
            g2l16(vg0 + vo, &vt_lds[nb][w * 8][0]);
        }
        const int buf = ti & 1;

        if (t0 <= q0 + 15) {
            f32x4 sf[4];
            #pragma unroll
            for (int kg = 0; kg < 4; kg++) {
                f32x4 s = {0, 0, 0, 0};
                const int row = kg * 16 + l16;
                #pragma unroll
                for (int kc = 0; kc < 4; kc++) {
                    const int slot = (kc * 4 + quad) ^ l16;
                    s = MFMA16(*(const bf16x8*)&kt_lds[buf][row][slot * 8], qa[kc], s);
                }
                sf[kg] = s;
            }

            const int qrow = q0 + l16;
            if (t0 + 63 > q0) {
                // diagonal tile: causal masking
                #pragma unroll
                for (int kg = 0; kg < 4; kg++) {
                    const int kbase = t0 + kg * 16 + quad * 4;
                    float v0 = (kbase     <= qrow) ? sf[kg][0] : -1e30f;
                    float v1 = (kbase + 1 <= qrow) ? sf[kg][1] : -1e30f;
                    float v2 = (kbase + 2 <= qrow) ? sf[kg][2] : -1e30f;
                    float v3 = (kbase + 3 <= qrow) ? sf[kg][3] : -1e30f;
                    ms = fmaxf(ms, fmaxf(fmaxf(v0, v1), fmaxf(v2, v3)));
                    const float e0 = __expf(v0), e1 = __expf(v1);
                    const float e2 = __expf(v2), e3 = __expf(v3);
                    ls += (e0 + e1) + (e2 + e3);
                    uint2 pk;
                    pk.x = pk2bf(e0, e1);
                    pk.y = pk2bf(e2, e3);
                    *(uint2*)&p_lds[w][l16][kg * 16 + quad * 4] = pk;
                }
            } else {
                // interior tile: no masking needed
                #pragma unroll
                for (int kg = 0; kg < 4; kg++) {
                    const float v0 = sf[kg][0], v1 = sf[kg][1];
                    const float v2 = sf[kg][2], v3 = sf[kg][3];
                    ms = fmaxf(ms, fmaxf(fmaxf(v0, v1), fmaxf(v2, v3)));
                    const float e0 = __expf(v0), e1 = __expf(v1);
                    const float e2 = __expf(v2), e3 = __expf(v3);
                    ls += (e0 + e1) + (e2 + e3);
                    uint2 pk;
                    pk.x = pk2bf(e0, e1);
                    pk.y = pk2bf(e2, e3);
                    *(uint2*)&p_lds[w][l16][kg * 16 + quad * 4] = pk;
                }
            }
            asm volatile("s_waitcnt lgkmcnt(0)" ::: "memory");
            bf16x8 pa0 = *(const bf16x8*)&p_lds[w][l16][quad * 8];
            bf16x8 pa1 = *(const bf16x8*)&p_lds[w][l16][quad * 8 + 32];

            #pragma unroll
            for (int dg = 0; dg < 4; dg++) {
                const int row = dg * 16 + l16;
                const int s0_ = quad ^ (l16 & 7);
                const int s1_ = (quad + 4) ^ (l16 & 7);
                o[dg] = MFMA16(pa0, *(const bf16x8*)&vt_lds[buf][row][s0_ * 8], o[dg]);
                o[dg] = MFMA16(pa1, *(const bf16x8*)&vt_lds[buf][row][s1_ * 8], o[dg]);
            }
        }
    }

    float mv = ms, lv = ls;
    mv = fmaxf(mv, __shfl_xor(mv, 16, 64)); lv += __shfl_xor(lv, 16, 64);
    mv = fmaxf(mv, __shfl_xor(mv, 32, 64)); lv += __shfl_xor(lv, 32, 64);
    const float inv = 1.f / (__expf(mv) + lv);

    #pragma unroll
    for (int r = 0; r < 4; r++) {
        const float ir = __shfl(inv, quad * 4 + r, 64);
        const int row = q0 + quad * 4 + r;
        const size_t base = (size_t)(b * S_ + row) * D_ + h * HD_ + l16;
        ao[base]      = f2b(o[0][r] * ir);
        ao[base + 16] = f2b(o[1][r] * ir);
        ao[base + 32] = f2b(o[2][r] * ir);
        ao[base + 48] = f2b(o[3][r] * ir);
    }
}

// ---------------------------------------------------------------------------
// LayerNorm over (ya + yb [+ res]); residual optional (fp32 or bf16, may be
// pre-added in the producing GEMM's epilogue). Vectorized float4 (G13).
// ---------------------------------------------------------------------------
__global__ __launch_bounds__(256) void ln_kernel(
    const float* __restrict__ ya, const float* __restrict__ yb,
    const float* __restrict__ resF, const unsigned short* __restrict__ resB,
    const float* __restrict__ g, const float* __restrict__ beta,
    float* __restrict__ outF, unsigned short* __restrict__ outB)
{
    const int row = blockIdx.x;
    const int tid = threadIdx.x;
    const int c = tid * 4;
    const size_t base = (size_t)row * D_ + c;

    float4 t4 = *(const float4*)(ya + base);
    if (yb) {
        float4 y4 = *(const float4*)(yb + base);
        t4.x += y4.x; t4.y += y4.y; t4.z += y4.z; t4.w += y4.w;
    }
    if (resF) {
        float4 r4 = *(const float4*)(resF + base);
        t4.x += r4.x; t4.y += r4.y; t4.z += r4.z; t4.w += r4.w;
    } else if (resB) {
        ushort4 r4 = *(const ushort4*)(resB + base);
        t4.x += b2f(r4.x); t4.y += b2f(r4.y); t4.z += b2f(r4.z); t4.w += b2f(r4.w);
    }
    float sum   = (t4.x + t4.y) + (t4.z + t4.w);
    float sumsq = (t4.x * t4.x + t4.y * t4.y) + (t4.z * t4.z + t4.w * t4.w);

    #pragma unroll
    for (int off = 32; off >= 1; off >>= 1) {
        sum   += __shfl_xor(sum,   off, 64);
        sumsq += __shfl_xor(sumsq, off, 64);
    }
    __shared__ float rs_[4], rq_[4];
    int w = tid >> 6, lane = tid & 63;
    if (lane == 0) { rs_[w] = sum; rq_[w] = sumsq; }
    __syncthreads();
    float tot  = rs_[0] + rs_[1] + rs_[2] + rs_[3];
    float totq = rq_[0] + rq_[1] + rq_[2] + rq_[3];
    float mu   = tot  * (1.f / D_);
    float var  = totq * (1.f / D_) - mu * mu;
    float rstd = rsqrtf(var + 1e-5f);

    float4 g4 = *(const float4*)(g + c);
    float4 b4 = *(const float4*)(beta + c);
    float4 o4;
    o4.x = (t4.x - mu) * rstd * g4.x + b4.x;
    o4.y = (t4.y - mu) * rstd * g4.y + b4.y;
    o4.z = (t4.z - mu) * rstd * g4.z + b4.z;
    o4.w = (t4.w - mu) * rstd * g4.w + b4.w;
    if (outF) *(float4*)(outF + base) = o4;
    if (outB) {
        ushort4 ob;
        ob.x = f2b(o4.x); ob.y = f2b(o4.y); ob.z = f2b(o4.z); ob.w = f2b(o4.w);
        *(ushort4*)(outB + base) = ob;
    }
}

// ---------------------------------------------------------------------------
extern "C" void kernel_launch(void* const* d_in, const int* in_sizes, int n_in,
                              void* d_out, int out_size, void* d_ws, size_t ws_size,
                              hipStream_t stream)
{
    const float* x   = (const float*)d_in[0];
    const float* Wq  = (const float*)d_in[2];
    const float* bq  = (const float*)d_in[3];
    const float* Wk  = (const float*)d_in[4];
    const float* bk  = (const float*)d_in[5];
    const float* Wv  = (const float*)d_in[6];
    const float* bv  = (const float*)d_in[7];
    const float* Wo  = (const float*)d_in[8];
    const float* bo  = (const float*)d_in[9];
    const float* phase_bias = (const float*)d_in[10];
    const float* freqs = (const float*)d_in[11];
    const float* W1  = (const float*)d_in[12];
    const float* b1  = (const float*)d_in[13];
    const float* W2  = (const float*)d_in[14];
    const float* b2  = (const float*)d_in[15];
    const float* g1  = (const float*)d_in[16];
    const float* be1 = (const float*)d_in[17];
    const float* g2  = (const float*)d_in[18];
    const float* be2 = (const float*)d_in[19];
    float* out = (float*)d_out;

    char* base = (char*)d_ws;
    const size_t MiB = 1024 * 1024;
    unsigned short* WqkvT = (unsigned short*)(base);             // [0,6)
    unsigned short* WoT   = (unsigned short*)(base + 6  * MiB);  // [6,8)
    unsigned short* W1T   = (unsigned short*)(base + 8  * MiB);  // [8,16)
    unsigned short* W2T   = (unsigned short*)(base + 16 * MiB);  // [16,24)
    float*          bqkv  = (float*)(base + 24 * MiB);           // [24,25)
    unsigned short* xb    = (unsigned short*)(base + 25 * MiB);  // [25,33)
    unsigned short* qkvb  = (unsigned short*)(base + 33 * MiB);  // [33,57)
    unsigned short* qpb   = (unsigned short*)(base + 57 * MiB);  // [57,73)
    unsigned short* kpb   = (unsigned short*)(base + 73 * MiB);  // [73,89)
    unsigned short* vtb   = (unsigned short*)(base + 89 * MiB);  // [89,97)
    float*          po    = (float*)(base + 89 * MiB);           // [89,121) 2 slices (vtb dead)
    unsigned short* aob   = xb;                                  // xb dead after QKV gemm
    unsigned short* x1b   = xb;                                  // aob dead after Wo gemm
    unsigned short* hb    = qkvb;                                // [33,65): qkvb+qpb dead
    float*          fo    = po;                                  // po dead after LN1

    dim3 blk(256);

    // prep: ONE fused launch (conv + bias concat + all 6 weight transposes)
    prep_kernel<<<dim3(16384), blk, 0, stream>>>(
        x, xb, bq, bk, bv, bqkv, Wq, Wk, Wv, Wo, WqkvT, WoT, W1, W1T, W2, W2T);

    // fused QKV projection -> bf16 qkvb
    gemm_bf16_kernel<<<dim3(3072 / 128, M_ / 128, 1), blk, 0, stream>>>(
        xb, WqkvT, bqkv, nullptr, nullptr, nullptr, qkvb, M_, D_, D_, 3072, 0);

    // PoPE + V transpose (one fused launch)
    popevt_kernel<<<dim3(5120), blk, 0, stream>>>(
        qkvb, phase_bias, freqs, qpb, kpb, vtb);

    // Flash attention
    attn_mfma_kernel<<<dim3(8, B_ * H_, 2), dim3(512), 0, stream>>>(qpb, kpb, vtb, aob);

    // Output projection (split-K=2, +x residual in epilogue) + LN1
    gemm_bf16_kernel<<<dim3(D_ / 128, M_ / 128, 2), blk, 0, stream>>>(
        aob, WoT, bo, x, nullptr, po, nullptr, M_, D_ / 2, D_, D_, 0);
    ln_kernel<<<dim3(M_), blk, 0, stream>>>(
        po, po + (size_t)M_ * D_, nullptr, nullptr, g1, be1, nullptr, x1b);

    // FFN (W2 epilogue adds x1b residual)
    gemm_bf16_kernel<<<dim3(DFF_ / 128, M_ / 128, 1), blk, 0, stream>>>(
        x1b, W1T, b1, nullptr, nullptr, nullptr, hb, M_, D_, D_, DFF_, 1);
    gemm_bf16_kernel<<<dim3(D_ / 128, M_ / 128, 2), blk, 0, stream>>>(
        hb, W2T, b2, nullptr, x1b, fo, nullptr, M_, DFF_ / 2, DFF_, D_, 0);
    ln_kernel<<<dim3(M_), blk, 0, stream>>>(
        fo, fo + (size_t)M_ * D_, nullptr, nullptr, g2, be2, out, nullptr);
}

// Round 9
// 376.662 us; speedup vs baseline: 1.0867x; 1.0867x over previous
//
#include <hip/hip_runtime.h>
#include <hip/hip_bf16.h>
#include <math.h>

#define B_   2
#define S_   2048
#define D_   1024
#define H_   16
#define HD_  64
#define DFF_ 4096
#define M_   (B_*S_)   // 4096 rows
#define SCALE_ 0.08838834764831845f  // 1/sqrt(128)

typedef __attribute__((ext_vector_type(8))) short bf16x8;
typedef __attribute__((ext_vector_type(4))) float f32x4;

#define MFMA16(a,b,c) __builtin_amdgcn_mfma_f32_16x16x32_bf16((a),(b),(c),0,0,0)

__device__ __forceinline__ unsigned short f2b(float f) {
    union { float f; unsigned u; } v; v.f = f;
    return (unsigned short)((v.u + 0x7FFFu + ((v.u >> 16) & 1u)) >> 16);
}
__device__ __forceinline__ float b2f(unsigned short s) {
    union { unsigned u; float f; } v; v.u = ((unsigned)s) << 16;
    return v.f;
}
// pack two f32 -> two bf16 (truncating) in ONE v_perm_b32
__device__ __forceinline__ unsigned pk2bf(float a, float b) {
    union { float f; unsigned u; } ua, ub; ua.f = a; ub.f = b;
    return __builtin_amdgcn_perm(ub.u, ua.u, 0x07060302u);
}
__device__ __forceinline__ float softplus_f(float x) {
    return fmaxf(x, 0.f) + log1pf(__expf(-fabsf(x)));
}
// async global->LDS, 16B per lane. LDS dest = base + lane*16 (wave-uniform base).
__device__ __forceinline__ void g2l16(const void* g, void* l) {
    __builtin_amdgcn_global_load_lds(
        (const __attribute__((address_space(1))) unsigned int*)g,
        (__attribute__((address_space(3))) unsigned int*)l, 16, 0, 0);
}

// ---------------------------------------------------------------------------
// Fused prep: ONE launch for x->bf16 conv (+bias concat), the 4 square
// weight transposes, W1T and W2T. All independent; block ranges:
//   [0,4096)       conv (+bqkv build in blocks 0..11)
//   [4096,8192)    wtrans4 (Wq/Wk/Wv/Wo, 1024 blocks each)
//   [8192,12288)   W1T: K=1024, N=4096
//   [12288,16384)  W2T: K=4096, N=1024
// ---------------------------------------------------------------------------
__global__ __launch_bounds__(256) void prep_kernel(
    const float* __restrict__ x, unsigned short* __restrict__ xb,
    const float* __restrict__ bq, const float* __restrict__ bk,
    const float* __restrict__ bv, float* __restrict__ bqkv,
    const float* __restrict__ Wq, const float* __restrict__ Wk,
    const float* __restrict__ Wv, const float* __restrict__ Wo,
    unsigned short* __restrict__ WqkvT, unsigned short* __restrict__ WoT,
    const float* __restrict__ W1, unsigned short* __restrict__ W1T,
    const float* __restrict__ W2, unsigned short* __restrict__ W2T)
{
    __shared__ float tile[32][33];
    const int bid = blockIdx.x;
    const int tid = threadIdx.x;

    if (bid < 4096) {
        // ---- conv + bias concat ----
        int i = (bid * 256 + tid) * 4;
        float4 v = *(const float4*)&x[i];
        ushort4 o;
        o.x = f2b(v.x); o.y = f2b(v.y); o.z = f2b(v.z); o.w = f2b(v.w);
        *(ushort4*)&xb[i] = o;
        int j = bid * 256 + tid;
        if (j < 3072)
            bqkv[j] = (j < 1024) ? bq[j] : (j < 2048 ? bk[j - 1024] : bv[j - 2048]);
        return;
    }

    // ---- transposes: pick source/dest and geometry ----
    const float* W; unsigned short* WT; int K, N, bx, by;
    if (bid < 8192) {
        const int idx = bid - 4096;           // 0..4095
        const int z = idx >> 10;              // 0..3
        W  = (z == 0) ? Wq : (z == 1) ? Wk : (z == 2) ? Wv : Wo;
        WT = (z < 3) ? WqkvT + (size_t)z * 1024 * 1024 : WoT;
        K = 1024; N = 1024;
        bx = idx & 31; by = (idx >> 5) & 31;
    } else if (bid < 12288) {
        const int idx = bid - 8192;           // 0..4095
        W = W1; WT = W1T; K = 1024; N = 4096;
        bx = idx & 127; by = idx >> 7;
    } else {
        const int idx = bid - 12288;          // 0..4095
        W = W2; WT = W2T; K = 4096; N = 1024;
        bx = idx & 31; by = idx >> 5;
    }
    const int n0 = bx * 32, k0 = by * 32;
    const int tx = tid & 31, ty = tid >> 5;   // ty 0..7
    #pragma unroll
    for (int i = 0; i < 4; i++)
        tile[ty + 8*i][tx] = W[(size_t)(k0 + ty + 8*i) * N + n0 + tx];
    __syncthreads();
    #pragma unroll
    for (int i = 0; i < 4; i++)
        WT[(size_t)(n0 + ty + 8*i) * K + k0 + tx] = f2b(tile[tx][ty + 8*i]);
}

// ---------------------------------------------------------------------------
// bf16 GEMM, 128^2 tile, BK=64, XOR-swizzled LDS, double-buffered staging,
// XCD-aware remap, optional split-K. C[M,N]=A[M,lda]@WT[N,lda]^T (+bias z=0).
// R9: epilogue kept CLEAN — R8 ledger: epilogue residual loads serialize
// against the store drain (no compute left to hide under) + zz==0 tail
// imbalance = +10us/gemm. Residual belongs in the streaming LN kernel.
// NOTE (R2 lesson): no libm calls in here (call-clobber -> acc spills).
// ---------------------------------------------------------------------------
__global__ __launch_bounds__(256) void gemm_bf16_kernel(
    const unsigned short* __restrict__ A,
    const unsigned short* __restrict__ WT,
    const float* __restrict__ bias,
    float* __restrict__ outF, unsigned short* __restrict__ outB,
    int M, int Kslice, int lda, int N, int relu)
{
    __shared__ unsigned short As[2][128 * 64];
    __shared__ unsigned short Bs[2][128 * 64];

    const int tid = threadIdx.x;
    const int w = tid >> 6, lane = tid & 63;
    const int quad = lane >> 4, l16 = lane & 15;

    const int nn = gridDim.x, nm = gridDim.y;
    const int lin = ((int)blockIdx.z * nm + (int)blockIdx.y) * nn + (int)blockIdx.x;
    const int per = (nn * nm * (int)gridDim.z) >> 3;
    const int id  = (lin & 7) * per + (lin >> 3);
    const int zz  = id / (nn * nm);
    const int rem = id - zz * nn * nm;
    const int mt_ = rem / nn, nt_ = rem - mt_ * nn;

    const size_t m0 = (size_t)mt_ * 128, n0 = (size_t)nt_ * 128;
    const int wm = (w >> 1) * 64, wn = (w & 1) * 64;
    const int koff = zz * Kslice;

    const int srow = lane >> 3;                       // 0..7 row within group
    const int sc   = ((lane & 7) ^ srow) * 8;         // swizzled global chunk
    const unsigned short* ga = A  + (m0 + w * 32 + srow) * (size_t)lda + koff + sc;
    const unsigned short* gb = WT + (n0 + w * 32 + srow) * (size_t)lda + koff + sc;
    const size_t rows8 = (size_t)8 * lda;

    f32x4 acc[4][4] = {};
    const int niter = Kslice >> 6;

    #pragma unroll
    for (int j = 0; j < 4; j++) g2l16(ga + j * rows8, &As[0][(w * 32 + j * 8) * 64]);
    #pragma unroll
    for (int j = 0; j < 4; j++) g2l16(gb + j * rows8, &Bs[0][(w * 32 + j * 8) * 64]);

    for (int i = 0; i < niter; i++) {
        __syncthreads();
        if (i + 1 < niter) {
            const int nb = (i + 1) & 1, k0 = (i + 1) << 6;
            #pragma unroll
            for (int j = 0; j < 4; j++)
                g2l16(ga + j * rows8 + k0, &As[nb][(w * 32 + j * 8) * 64]);
            #pragma unroll
            for (int j = 0; j < 4; j++)
                g2l16(gb + j * rows8 + k0, &Bs[nb][(w * 32 + j * 8) * 64]);
        }
        const int buf = i & 1;

        #pragma unroll
        for (int kk = 0; kk < 2; kk++) {
            bf16x8 af[4], bfr[4];
            #pragma unroll
            for (int t = 0; t < 4; t++) {
                const int slot = ((kk * 4 + quad) ^ (l16 & 7)) * 8;
                af[t]  = *(const bf16x8*)&As[buf][(wm + t * 16 + l16) * 64 + slot];
                bfr[t] = *(const bf16x8*)&Bs[buf][(wn + t * 16 + l16) * 64 + slot];
            }
            #pragma unroll
            for (int mt = 0; mt < 4; mt++)
                #pragma unroll
                for (int nt = 0; nt < 4; nt++)
                    acc[mt][nt] = MFMA16(af[mt], bfr[nt], acc[mt][nt]);
        }
    }

    float bv[4];
    #pragma unroll
    for (int nt = 0; nt < 4; nt++)
        bv[nt] = (zz == 0) ? bias[n0 + wn + nt * 16 + l16] : 0.f;

    float* outFz = outF ? outF + (size_t)zz * M * N : nullptr;

    #pragma unroll
    for (int mt = 0; mt < 4; mt++) {
        #pragma unroll
        for (int nt = 0; nt < 4; nt++) {
            const size_t n = n0 + wn + nt * 16 + l16;
            #pragma unroll
            for (int r = 0; r < 4; r++) {
                const size_t m = m0 + wm + mt * 16 + quad * 4 + r;
                float val = acc[mt][nt][r] + bv[nt];
                if (relu) val = fmaxf(val, 0.f);
                const size_t idx = m * N + n;
                if (outFz) outFz[idx] = val;
                if (outB) outB[idx] = f2b(val);
            }
        }
    }
}

// ---------------------------------------------------------------------------
// Fused PoPE + V transpose, one launch (both read only qkvb):
//   [0,4096)      PoPE: qkvb -> qp,kp (vectorized ushort4, __sincosf)
//   [4096,5120)   V transpose: qkvb col 2048.. -> vt (B*H, 64, S)
// ---------------------------------------------------------------------------
__global__ __launch_bounds__(256) void popevt_kernel(
    const unsigned short* __restrict__ qkv,
    const float* __restrict__ phase_bias, const float* __restrict__ freqs,
    unsigned short* __restrict__ qp, unsigned short* __restrict__ kp,
    unsigned short* __restrict__ vt)
{
    __shared__ unsigned short tile[64][68];
    const int bid = blockIdx.x;
    const int tid = threadIdx.x;

    if (bid < 4096) {
        // ---- PoPE ----
        int idx = bid * 256 + tid;              // over B*H*S*16
        int d4 = (idx & 15) * 4;
        int s  = (idx >> 4) & (S_ - 1);
        int h  = (idx >> 15) & (H_ - 1);
        int b  = idx >> 19;

        size_t src = (size_t)(b * S_ + s) * 3072 + h * HD_ + d4;
        ushort4 qv = *(const ushort4*)&qkv[src];
        ushort4 kv = *(const ushort4*)&qkv[src + 1024];
        float4 fr = *(const float4*)&freqs[d4];
        float4 pb = *(const float4*)&phase_bias[h * HD_ + d4];
        const float fs = (float)s;

        ushort4 qc4, qs4, kc4, ks4;
        {
            float muq = softplus_f(b2f(qv.x)) * SCALE_, muk = softplus_f(b2f(kv.x));
            float sn, cs; __sincosf(fs * fr.x + pb.x, &sn, &cs);
            qc4.x = f2b(muq * cs); qs4.x = f2b(muq * sn);
            kc4.x = f2b(muk * cs); ks4.x = f2b(muk * sn);
        }
        {
            float muq = softplus_f(b2f(qv.y)) * SCALE_, muk = softplus_f(b2f(kv.y));
            float sn, cs; __sincosf(fs * fr.y + pb.y, &sn, &cs);
            qc4.y = f2b(muq * cs); qs4.y = f2b(muq * sn);
            kc4.y = f2b(muk * cs); ks4.y = f2b(muk * sn);
        }
        {
            float muq = softplus_f(b2f(qv.z)) * SCALE_, muk = softplus_f(b2f(kv.z));
            float sn, cs; __sincosf(fs * fr.z + pb.z, &sn, &cs);
            qc4.z = f2b(muq * cs); qs4.z = f2b(muq * sn);
            kc4.z = f2b(muk * cs); ks4.z = f2b(muk * sn);
        }
        {
            float muq = softplus_f(b2f(qv.w)) * SCALE_, muk = softplus_f(b2f(kv.w));
            float sn, cs; __sincosf(fs * fr.w + pb.w, &sn, &cs);
            qc4.w = f2b(muq * cs); qs4.w = f2b(muq * sn);
            kc4.w = f2b(muk * cs); ks4.w = f2b(muk * sn);
        }

        size_t o = ((size_t)(b * H_ + h) * S_ + s) * 128 + d4;
        *(ushort4*)&qp[o]      = qc4;
        *(ushort4*)&qp[o + 64] = qs4;
        *(ushort4*)&kp[o]      = kc4;
        *(ushort4*)&kp[o + 64] = ks4;
        return;
    }

    // ---- V transpose ----
    const int idx0 = bid - 4096;                 // 0..1023
    const int bh = idx0 >> 5, b = bh >> 4, h = bh & 15;
    const int s0 = (idx0 & 31) * 64;
    #pragma unroll
    for (int i = 0; i < 4; i++) {
        int idx = i * 256 + tid;                 // 64s x 16 d-quads
        int s = idx >> 4, d4 = (idx & 15) * 4;
        *(ushort4*)&tile[s][d4] =
            *(const ushort4*)&qkv[(size_t)(b * S_ + s0 + s) * 3072 + 2048 + h * HD_ + d4];
    }
    __syncthreads();
    #pragma unroll
    for (int i = 0; i < 4; i++) {
        int idx = i * 256 + tid;                 // 64d x 16 s-quads
        int d = idx >> 4, s4 = (idx & 15) * 4;
        ushort4 o;
        o.x = tile[s4][d]; o.y = tile[s4 + 1][d];
        o.z = tile[s4 + 2][d]; o.w = tile[s4 + 3][d];
        *(ushort4*)&vt[((size_t)bh * 64 + d) * S_ + s0 + s4] = o;
    }
}

// ---------------------------------------------------------------------------
// MFMA flash attention: softmax1, lazy normalization, S^T trick,
// 128 q rows/block, dbuf K/V staging, causal split over grid.z.
// R9: exact R5/R7 structure (proven 53.6-54.6us). Ledger of failed edits:
// setprio (+1.4us, m190 lockstep), shfl-P-redistr (+9.3us, bank conflicts +
// VGPR squeeze), depth-2 vmcnt (+7.0us: 1 blk/CU killed TLP + L2 reuse),
// R8 dmask-branch (confounded with GEMM regression; not retained).
// ---------------------------------------------------------------------------
__global__ __launch_bounds__(512, 4) void attn_mfma_kernel(
    const unsigned short* __restrict__ qp,
    const unsigned short* __restrict__ kp,
    const unsigned short* __restrict__ vt,
    unsigned short* __restrict__ ao)
{
    __shared__ unsigned short kt_lds[2][64][128];  // [buf][key][k], chunk^=(key&15)
    __shared__ unsigned short vt_lds[2][64][64];   // [buf][d][key], chunk^=(d&7)
    __shared__ unsigned short p_lds[8][16][72];    // per-wave P: [q][key]

    const int tid = threadIdx.x;
    const int w = tid >> 6, lane = tid & 63;
    const int quad = lane >> 4, l16 = lane & 15;
    const int bh = blockIdx.y, b = bh >> 4, h = bh & 15;

    const int a = (blockIdx.z == 0) ? 15 - (int)blockIdx.x : (int)blockIdx.x;
    const int q0b = a * 128;
    const int q0 = q0b + w * 16;

    const unsigned short* qbase = qp + ((size_t)bh * S_ + q0 + l16) * 128 + quad * 8;
    bf16x8 qa[4];
    #pragma unroll
    for (int kc = 0; kc < 4; kc++) qa[kc] = *(const bf16x8*)(qbase + kc * 32);

    const int krow = lane >> 4, kslot = lane & 15;
    const int vrow = lane >> 3, vslot = lane & 7;
    const int kr0 = w * 8 + krow,     kc0 = kslot ^ (kr0 & 15);
    const int kr1 = w * 8 + 4 + krow, kc1 = kslot ^ (kr1 & 15);
    const int vd  = w * 8 + vrow,     vc  = vslot ^ (vd & 7);
    const unsigned short* kg0 = kp + ((size_t)bh * S_ + kr0) * 128 + kc0 * 8;
    const unsigned short* kg1 = kp + ((size_t)bh * S_ + kr1) * 128 + kc1 * 8;
    const unsigned short* vg0 = vt + ((size_t)bh * 64 + vd) * S_ + vc * 8;

    f32x4 o[4] = {};
    float ms = -1e30f, ls = 0.f;

    const int ntiles = 2 * a + 2;

    g2l16(kg0, &kt_lds[0][w * 8][0]);
    g2l16(kg1, &kt_lds[0][w * 8 + 4][0]);
    g2l16(vg0, &vt_lds[0][w * 8][0]);

    for (int ti = 0; ti < ntiles; ti++) {
        const int t0 = ti * 64;
        __syncthreads();
        if (ti + 1 < ntiles) {
            const int nb = (ti + 1) & 1;
            const size_t ko = (size_t)(ti + 1) * (64 * 128);
            const size_t vo = (size_t)(ti + 1) * 64;
            g2l16(kg0 + ko, &kt_lds[nb][w * 8][0]);
            g2l16(kg1 + ko, &kt_lds[nb][w * 8 + 4][0]);
            g2l16(vg0 + vo, &vt_lds[nb][w * 8][0]);
        }
        const int buf = ti & 1;

        if (t0 <= q0 + 15) {
            f32x4 sf[4];
            #pragma unroll
            for (int kg = 0; kg < 4; kg++) {
                f32x4 s = {0, 0, 0, 0};
                const int row = kg * 16 + l16;
                #pragma unroll
                for (int kc = 0; kc < 4; kc++) {
                    const int slot = (kc * 4 + quad) ^ l16;
                    s = MFMA16(*(const bf16x8*)&kt_lds[buf][row][slot * 8], qa[kc], s);
                }
                sf[kg] = s;
            }

            const int qrow = q0 + l16;
            const bool dmask = (t0 + 63 > q0);
            #pragma unroll
            for (int kg = 0; kg < 4; kg++) {
                const int kbase = t0 + kg * 16 + quad * 4;
                float v0 = sf[kg][0], v1 = sf[kg][1], v2 = sf[kg][2], v3 = sf[kg][3];
                if (dmask) {
                    v0 = (kbase     <= qrow) ? v0 : -1e30f;
                    v1 = (kbase + 1 <= qrow) ? v1 : -1e30f;
                    v2 = (kbase + 2 <= qrow) ? v2 : -1e30f;
                    v3 = (kbase + 3 <= qrow) ? v3 : -1e30f;
                }
                ms = fmaxf(ms, fmaxf(fmaxf(v0, v1), fmaxf(v2, v3)));
                const float e0 = __expf(v0), e1 = __expf(v1);
                const float e2 = __expf(v2), e3 = __expf(v3);
                ls += (e0 + e1) + (e2 + e3);
                uint2 pk;
                pk.x = pk2bf(e0, e1);
                pk.y = pk2bf(e2, e3);
                *(uint2*)&p_lds[w][l16][kg * 16 + quad * 4] = pk;
            }
            asm volatile("s_waitcnt lgkmcnt(0)" ::: "memory");
            bf16x8 pa0 = *(const bf16x8*)&p_lds[w][l16][quad * 8];
            bf16x8 pa1 = *(const bf16x8*)&p_lds[w][l16][quad * 8 + 32];

            #pragma unroll
            for (int dg = 0; dg < 4; dg++) {
                const int row = dg * 16 + l16;
                const int s0_ = quad ^ (l16 & 7);
                const int s1_ = (quad + 4) ^ (l16 & 7);
                o[dg] = MFMA16(pa0, *(const bf16x8*)&vt_lds[buf][row][s0_ * 8], o[dg]);
                o[dg] = MFMA16(pa1, *(const bf16x8*)&vt_lds[buf][row][s1_ * 8], o[dg]);
            }
        }
    }

    float mv = ms, lv = ls;
    mv = fmaxf(mv, __shfl_xor(mv, 16, 64)); lv += __shfl_xor(lv, 16, 64);
    mv = fmaxf(mv, __shfl_xor(mv, 32, 64)); lv += __shfl_xor(lv, 32, 64);
    const float inv = 1.f / (__expf(mv) + lv);

    #pragma unroll
    for (int r = 0; r < 4; r++) {
        const float ir = __shfl(inv, quad * 4 + r, 64);
        const int row = q0 + quad * 4 + r;
        const size_t base = (size_t)(b * S_ + row) * D_ + h * HD_ + l16;
        ao[base]      = f2b(o[0][r] * ir);
        ao[base + 16] = f2b(o[1][r] * ir);
        ao[base + 32] = f2b(o[2][r] * ir);
        ao[base + 48] = f2b(o[3][r] * ir);
    }
}

// ---------------------------------------------------------------------------
// Residual + LayerNorm over (ya + yb + res); residual fp32 OR bf16;
// outputs fp32 and/or bf16 (either may be null). Vectorized float4 (G13).
// R9: residual reads restored here — streaming, coalesced, overlapped
// across blocks (R8 showed GEMM-epilogue placement costs ~10us/gemm).
// ---------------------------------------------------------------------------
__global__ __launch_bounds__(256) void ln_kernel(
    const float* __restrict__ ya, const float* __restrict__ yb,
    const float* __restrict__ resF, const unsigned short* __restrict__ resB,
    const float* __restrict__ g, const float* __restrict__ beta,
    float* __restrict__ outF, unsigned short* __restrict__ outB)
{
    const int row = blockIdx.x;
    const int tid = threadIdx.x;
    const int c = tid * 4;
    const size_t base = (size_t)row * D_ + c;

    float4 t4 = *(const float4*)(ya + base);
    if (yb) {
        float4 y4 = *(const float4*)(yb + base);
        t4.x += y4.x; t4.y += y4.y; t4.z += y4.z; t4.w += y4.w;
    }
    if (resF) {
        float4 r4 = *(const float4*)(resF + base);
        t4.x += r4.x; t4.y += r4.y; t4.z += r4.z; t4.w += r4.w;
    } else if (resB) {
        ushort4 r4 = *(const ushort4*)(resB + base);
        t4.x += b2f(r4.x); t4.y += b2f(r4.y); t4.z += b2f(r4.z); t4.w += b2f(r4.w);
    }
    float sum   = (t4.x + t4.y) + (t4.z + t4.w);
    float sumsq = (t4.x * t4.x + t4.y * t4.y) + (t4.z * t4.z + t4.w * t4.w);

    #pragma unroll
    for (int off = 32; off >= 1; off >>= 1) {
        sum   += __shfl_xor(sum,   off, 64);
        sumsq += __shfl_xor(sumsq, off, 64);
    }
    __shared__ float rs_[4], rq_[4];
    int w = tid >> 6, lane = tid & 63;
    if (lane == 0) { rs_[w] = sum; rq_[w] = sumsq; }
    __syncthreads();
    float tot  = rs_[0] + rs_[1] + rs_[2] + rs_[3];
    float totq = rq_[0] + rq_[1] + rq_[2] + rq_[3];
    float mu   = tot  * (1.f / D_);
    float var  = totq * (1.f / D_) - mu * mu;
    float rstd = rsqrtf(var + 1e-5f);

    float4 g4 = *(const float4*)(g + c);
    float4 b4 = *(const float4*)(beta + c);
    float4 o4;
    o4.x = (t4.x - mu) * rstd * g4.x + b4.x;
    o4.y = (t4.y - mu) * rstd * g4.y + b4.y;
    o4.z = (t4.z - mu) * rstd * g4.z + b4.z;
    o4.w = (t4.w - mu) * rstd * g4.w + b4.w;
    if (outF) *(float4*)(outF + base) = o4;
    if (outB) {
        ushort4 ob;
        ob.x = f2b(o4.x); ob.y = f2b(o4.y); ob.z = f2b(o4.z); ob.w = f2b(o4.w);
        *(ushort4*)(outB + base) = ob;
    }
}

// ---------------------------------------------------------------------------
extern "C" void kernel_launch(void* const* d_in, const int* in_sizes, int n_in,
                              void* d_out, int out_size, void* d_ws, size_t ws_size,
                              hipStream_t stream)
{
    const float* x   = (const float*)d_in[0];
    const float* Wq  = (const float*)d_in[2];
    const float* bq  = (const float*)d_in[3];
    const float* Wk  = (const float*)d_in[4];
    const float* bk  = (const float*)d_in[5];
    const float* Wv  = (const float*)d_in[6];
    const float* bv  = (const float*)d_in[7];
    const float* Wo  = (const float*)d_in[8];
    const float* bo  = (const float*)d_in[9];
    const float* phase_bias = (const float*)d_in[10];
    const float* freqs = (const float*)d_in[11];
    const float* W1  = (const float*)d_in[12];
    const float* b1  = (const float*)d_in[13];
    const float* W2  = (const float*)d_in[14];
    const float* b2  = (const float*)d_in[15];
    const float* g1  = (const float*)d_in[16];
    const float* be1 = (const float*)d_in[17];
    const float* g2  = (const float*)d_in[18];
    const float* be2 = (const float*)d_in[19];
    float* out = (float*)d_out;

    char* base = (char*)d_ws;
    const size_t MiB = 1024 * 1024;
    unsigned short* WqkvT = (unsigned short*)(base);             // [0,6)
    unsigned short* WoT   = (unsigned short*)(base + 6  * MiB);  // [6,8)
    unsigned short* W1T   = (unsigned short*)(base + 8  * MiB);  // [8,16)
    unsigned short* W2T   = (unsigned short*)(base + 16 * MiB);  // [16,24)
    float*          bqkv  = (float*)(base + 24 * MiB);           // [24,25)
    unsigned short* xb    = (unsigned short*)(base + 25 * MiB);  // [25,33)
    unsigned short* qkvb  = (unsigned short*)(base + 33 * MiB);  // [33,57)
    unsigned short* qpb   = (unsigned short*)(base + 57 * MiB);  // [57,73)
    unsigned short* kpb   = (unsigned short*)(base + 73 * MiB);  // [73,89)
    unsigned short* vtb   = (unsigned short*)(base + 89 * MiB);  // [89,97)
    float*          po    = (float*)(base + 89 * MiB);           // [89,121) 2 slices (vtb dead)
    unsigned short* aob   = xb;                                  // xb dead after QKV gemm
    unsigned short* x1b   = xb;                                  // aob dead after Wo gemm
    unsigned short* hb    = qkvb;                                // [33,65): qkvb+qpb dead
    float*          fo    = po;                                  // po dead after LN1

    dim3 blk(256);

    // prep: ONE fused launch (conv + bias concat + all 6 weight transposes)
    prep_kernel<<<dim3(16384), blk, 0, stream>>>(
        x, xb, bq, bk, bv, bqkv, Wq, Wk, Wv, Wo, WqkvT, WoT, W1, W1T, W2, W2T);

    // fused QKV projection -> bf16 qkvb
    gemm_bf16_kernel<<<dim3(3072 / 128, M_ / 128, 1), blk, 0, stream>>>(
        xb, WqkvT, bqkv, nullptr, qkvb, M_, D_, D_, 3072, 0);

    // PoPE + V transpose (one fused launch)
    popevt_kernel<<<dim3(5120), blk, 0, stream>>>(
        qkvb, phase_bias, freqs, qpb, kpb, vtb);

    // Flash attention
    attn_mfma_kernel<<<dim3(8, B_ * H_, 2), dim3(512), 0, stream>>>(qpb, kpb, vtb, aob);

    // Output projection (split-K=2) + LN1 (bf16-only output)
    gemm_bf16_kernel<<<dim3(D_ / 128, M_ / 128, 2), blk, 0, stream>>>(
        aob, WoT, bo, po, nullptr, M_, D_ / 2, D_, D_, 0);
    ln_kernel<<<dim3(M_), blk, 0, stream>>>(
        po, po + (size_t)M_ * D_, x, nullptr, g1, be1, nullptr, x1b);

    // FFN
    gemm_bf16_kernel<<<dim3(DFF_ / 128, M_ / 128, 1), blk, 0, stream>>>(
        x1b, W1T, b1, nullptr, hb, M_, D_, D_, DFF_, 1);
    gemm_bf16_kernel<<<dim3(D_ / 128, M_ / 128, 2), blk, 0, stream>>>(
        hb, W2T, b2, fo, nullptr, M_, DFF_ / 2, DFF_, D_, 0);
    ln_kernel<<<dim3(M_), blk, 0, stream>>>(
        fo, fo + (size_t)M_ * D_, nullptr, x1b, g2, be2, out, nullptr);
}

// Round 10
// 366.002 us; speedup vs baseline: 1.1184x; 1.0291x over previous
//
#include <hip/hip_runtime.h>
#include <hip/hip_bf16.h>
#include <math.h>

#define B_   2
#define S_   2048
#define D_   1024
#define H_   16
#define HD_  64
#define DFF_ 4096
#define M_   (B_*S_)   // 4096 rows
#define SCALE_ 0.08838834764831845f  // 1/sqrt(128)

typedef __attribute__((ext_vector_type(8))) short bf16x8;
typedef __attribute__((ext_vector_type(4))) float f32x4;

#define MFMA16(a,b,c) __builtin_amdgcn_mfma_f32_16x16x32_bf16((a),(b),(c),0,0,0)

__device__ __forceinline__ unsigned short f2b(float f) {
    union { float f; unsigned u; } v; v.f = f;
    return (unsigned short)((v.u + 0x7FFFu + ((v.u >> 16) & 1u)) >> 16);
}
__device__ __forceinline__ float b2f(unsigned short s) {
    union { unsigned u; float f; } v; v.u = ((unsigned)s) << 16;
    return v.f;
}
// pack two f32 -> two bf16 (truncating) in ONE v_perm_b32
__device__ __forceinline__ unsigned pk2bf(float a, float b) {
    union { float f; unsigned u; } ua, ub; ua.f = a; ub.f = b;
    return __builtin_amdgcn_perm(ub.u, ua.u, 0x07060302u);
}
__device__ __forceinline__ float softplus_f(float x) {
    return fmaxf(x, 0.f) + log1pf(__expf(-fabsf(x)));
}
// ALL-INLINE softplus for use inside MFMA kernels (R2 lesson: libm calls
// (sincosf/log1pf) clobber VGPRs -> acc spills -> 1GB scratch, 8x slowdown).
// __logf/__expf are inline v_log/v_exp; err ~1e-6 << bf16 rounding.
__device__ __forceinline__ float softplus_i(float x) {
    return fmaxf(x, 0.f) + __logf(1.f + __expf(-fabsf(x)));
}
// async global->LDS, 16B per lane. LDS dest = base + lane*16 (wave-uniform base).
__device__ __forceinline__ void g2l16(const void* g, void* l) {
    __builtin_amdgcn_global_load_lds(
        (const __attribute__((address_space(1))) unsigned int*)g,
        (__attribute__((address_space(3))) unsigned int*)l, 16, 0, 0);
}

// ---------------------------------------------------------------------------
// Fused prep: ONE launch for x->bf16 conv (+bias concat), the 4 square
// weight transposes, W1T and W2T. All independent; block ranges:
//   [0,4096)       conv (+bqkv build in blocks 0..11)
//   [4096,8192)    wtrans4 (Wq/Wk/Wv/Wo, 1024 blocks each)
//   [8192,12288)   W1T: K=1024, N=4096
//   [12288,16384)  W2T: K=4096, N=1024
// ---------------------------------------------------------------------------
__global__ __launch_bounds__(256) void prep_kernel(
    const float* __restrict__ x, unsigned short* __restrict__ xb,
    const float* __restrict__ bq, const float* __restrict__ bk,
    const float* __restrict__ bv, float* __restrict__ bqkv,
    const float* __restrict__ Wq, const float* __restrict__ Wk,
    const float* __restrict__ Wv, const float* __restrict__ Wo,
    unsigned short* __restrict__ WqkvT, unsigned short* __restrict__ WoT,
    const float* __restrict__ W1, unsigned short* __restrict__ W1T,
    const float* __restrict__ W2, unsigned short* __restrict__ W2T)
{
    __shared__ float tile[32][33];
    const int bid = blockIdx.x;
    const int tid = threadIdx.x;

    if (bid < 4096) {
        // ---- conv + bias concat ----
        int i = (bid * 256 + tid) * 4;
        float4 v = *(const float4*)&x[i];
        ushort4 o;
        o.x = f2b(v.x); o.y = f2b(v.y); o.z = f2b(v.z); o.w = f2b(v.w);
        *(ushort4*)&xb[i] = o;
        int j = bid * 256 + tid;
        if (j < 3072)
            bqkv[j] = (j < 1024) ? bq[j] : (j < 2048 ? bk[j - 1024] : bv[j - 2048]);
        return;
    }

    // ---- transposes: pick source/dest and geometry ----
    const float* W; unsigned short* WT; int K, N, bx, by;
    if (bid < 8192) {
        const int idx = bid - 4096;           // 0..4095
        const int z = idx >> 10;              // 0..3
        W  = (z == 0) ? Wq : (z == 1) ? Wk : (z == 2) ? Wv : Wo;
        WT = (z < 3) ? WqkvT + (size_t)z * 1024 * 1024 : WoT;
        K = 1024; N = 1024;
        bx = idx & 31; by = (idx >> 5) & 31;
    } else if (bid < 12288) {
        const int idx = bid - 8192;           // 0..4095
        W = W1; WT = W1T; K = 1024; N = 4096;
        bx = idx & 127; by = idx >> 7;
    } else {
        const int idx = bid - 12288;          // 0..4095
        W = W2; WT = W2T; K = 4096; N = 1024;
        bx = idx & 31; by = idx >> 5;
    }
    const int n0 = bx * 32, k0 = by * 32;
    const int tx = tid & 31, ty = tid >> 5;   // ty 0..7
    #pragma unroll
    for (int i = 0; i < 4; i++)
        tile[ty + 8*i][tx] = W[(size_t)(k0 + ty + 8*i) * N + n0 + tx];
    __syncthreads();
    #pragma unroll
    for (int i = 0; i < 4; i++)
        WT[(size_t)(n0 + ty + 8*i) * K + k0 + tx] = f2b(tile[tx][ty + 8*i]);
}

// ---------------------------------------------------------------------------
// bf16 GEMM, 128^2 tile, BK=64, XOR-swizzled LDS, double-buffered staging,
// XCD-aware remap, optional split-K. C[M,N]=A[M,lda]@WT[N,lda]^T (+bias z=0).
// Epilogue kept CLEAN (R8: epilogue loads serialize against store drain).
// ---------------------------------------------------------------------------
__global__ __launch_bounds__(256) void gemm_bf16_kernel(
    const unsigned short* __restrict__ A,
    const unsigned short* __restrict__ WT,
    const float* __restrict__ bias,
    float* __restrict__ outF, unsigned short* __restrict__ outB,
    int M, int Kslice, int lda, int N, int relu)
{
    __shared__ unsigned short As[2][128 * 64];
    __shared__ unsigned short Bs[2][128 * 64];

    const int tid = threadIdx.x;
    const int w = tid >> 6, lane = tid & 63;
    const int quad = lane >> 4, l16 = lane & 15;

    const int nn = gridDim.x, nm = gridDim.y;
    const int lin = ((int)blockIdx.z * nm + (int)blockIdx.y) * nn + (int)blockIdx.x;
    const int per = (nn * nm * (int)gridDim.z) >> 3;
    const int id  = (lin & 7) * per + (lin >> 3);
    const int zz  = id / (nn * nm);
    const int rem = id - zz * nn * nm;
    const int mt_ = rem / nn, nt_ = rem - mt_ * nn;

    const size_t m0 = (size_t)mt_ * 128, n0 = (size_t)nt_ * 128;
    const int wm = (w >> 1) * 64, wn = (w & 1) * 64;
    const int koff = zz * Kslice;

    const int srow = lane >> 3;                       // 0..7 row within group
    const int sc   = ((lane & 7) ^ srow) * 8;         // swizzled global chunk
    const unsigned short* ga = A  + (m0 + w * 32 + srow) * (size_t)lda + koff + sc;
    const unsigned short* gb = WT + (n0 + w * 32 + srow) * (size_t)lda + koff + sc;
    const size_t rows8 = (size_t)8 * lda;

    f32x4 acc[4][4] = {};
    const int niter = Kslice >> 6;

    #pragma unroll
    for (int j = 0; j < 4; j++) g2l16(ga + j * rows8, &As[0][(w * 32 + j * 8) * 64]);
    #pragma unroll
    for (int j = 0; j < 4; j++) g2l16(gb + j * rows8, &Bs[0][(w * 32 + j * 8) * 64]);

    for (int i = 0; i < niter; i++) {
        __syncthreads();
        if (i + 1 < niter) {
            const int nb = (i + 1) & 1, k0 = (i + 1) << 6;
            #pragma unroll
            for (int j = 0; j < 4; j++)
                g2l16(ga + j * rows8 + k0, &As[nb][(w * 32 + j * 8) * 64]);
            #pragma unroll
            for (int j = 0; j < 4; j++)
                g2l16(gb + j * rows8 + k0, &Bs[nb][(w * 32 + j * 8) * 64]);
        }
        const int buf = i & 1;

        #pragma unroll
        for (int kk = 0; kk < 2; kk++) {
            bf16x8 af[4], bfr[4];
            #pragma unroll
            for (int t = 0; t < 4; t++) {
                const int slot = ((kk * 4 + quad) ^ (l16 & 7)) * 8;
                af[t]  = *(const bf16x8*)&As[buf][(wm + t * 16 + l16) * 64 + slot];
                bfr[t] = *(const bf16x8*)&Bs[buf][(wn + t * 16 + l16) * 64 + slot];
            }
            #pragma unroll
            for (int mt = 0; mt < 4; mt++)
                #pragma unroll
                for (int nt = 0; nt < 4; nt++)
                    acc[mt][nt] = MFMA16(af[mt], bfr[nt], acc[mt][nt]);
        }
    }

    float bv[4];
    #pragma unroll
    for (int nt = 0; nt < 4; nt++)
        bv[nt] = (zz == 0) ? bias[n0 + wn + nt * 16 + l16] : 0.f;

    float* outFz = outF ? outF + (size_t)zz * M * N : nullptr;

    #pragma unroll
    for (int mt = 0; mt < 4; mt++) {
        #pragma unroll
        for (int nt = 0; nt < 4; nt++) {
            const size_t n = n0 + wn + nt * 16 + l16;
            #pragma unroll
            for (int r = 0; r < 4; r++) {
                const size_t m = m0 + wm + mt * 16 + quad * 4 + r;
                float val = acc[mt][nt][r] + bv[nt];
                if (relu) val = fmaxf(val, 0.f);
                const size_t idx = m * N + n;
                if (outFz) outFz[idx] = val;
                if (outB) outB[idx] = f2b(val);
            }
        }
    }
}

// ---------------------------------------------------------------------------
// QKV GEMM + fused PoPE + fused V-transpose epilogue. Same 128^2 main loop.
// N=3072, K=lda=1024, no split-K. n-tiles are uniformly q (n0<1024),
// k (n0<2048) or v (n0>=2048): q/k tiles apply softplus+phase -> qp/kp;
// v tiles write bf16 DIRECTLY TRANSPOSED into vt (B*H, 64, S) — qkvb is
// never materialized, popevt kernel deleted.
// R2 RETRY with root cause fixed: ALL math inline (__sincosf/__expf/__logf,
// no libm calls -> no call-clobber -> no acc spills). Watch: VGPR<=~130,
// WRITE_SIZE ~41MB. R2's spill signature was VGPR 92 + WRITE_SIZE 1GB.
// ---------------------------------------------------------------------------
__global__ __launch_bounds__(256) void gemm_qkv_pope_kernel(
    const unsigned short* __restrict__ A,
    const unsigned short* __restrict__ WT,
    const float* __restrict__ bias,
    const float* __restrict__ phase_bias, const float* __restrict__ freqs,
    unsigned short* __restrict__ qp, unsigned short* __restrict__ kp,
    unsigned short* __restrict__ vt)
{
    __shared__ unsigned short As[2][128 * 64];
    __shared__ unsigned short Bs[2][128 * 64];

    const int tid = threadIdx.x;
    const int w = tid >> 6, lane = tid & 63;
    const int quad = lane >> 4, l16 = lane & 15;

    const int nn = gridDim.x, nm = gridDim.y;   // 24 x 32
    const int lin = (int)blockIdx.y * nn + (int)blockIdx.x;
    const int per = (nn * nm) >> 3;
    const int id  = (lin & 7) * per + (lin >> 3);
    const int mt_ = id / nn, nt_ = id - mt_ * nn;

    const size_t m0 = (size_t)mt_ * 128, n0 = (size_t)nt_ * 128;
    const int wm = (w >> 1) * 64, wn = (w & 1) * 64;

    const int srow = lane >> 3;
    const int sc   = ((lane & 7) ^ srow) * 8;
    const unsigned short* ga = A  + (m0 + w * 32 + srow) * (size_t)D_ + sc;
    const unsigned short* gb = WT + (n0 + w * 32 + srow) * (size_t)D_ + sc;
    const size_t rows8 = (size_t)8 * D_;

    f32x4 acc[4][4] = {};
    const int niter = D_ >> 6;   // 16

    #pragma unroll
    for (int j = 0; j < 4; j++) g2l16(ga + j * rows8, &As[0][(w * 32 + j * 8) * 64]);
    #pragma unroll
    for (int j = 0; j < 4; j++) g2l16(gb + j * rows8, &Bs[0][(w * 32 + j * 8) * 64]);

    for (int i = 0; i < niter; i++) {
        __syncthreads();
        if (i + 1 < niter) {
            const int nb = (i + 1) & 1, k0 = (i + 1) << 6;
            #pragma unroll
            for (int j = 0; j < 4; j++)
                g2l16(ga + j * rows8 + k0, &As[nb][(w * 32 + j * 8) * 64]);
            #pragma unroll
            for (int j = 0; j < 4; j++)
                g2l16(gb + j * rows8 + k0, &Bs[nb][(w * 32 + j * 8) * 64]);
        }
        const int buf = i & 1;

        #pragma unroll
        for (int kk = 0; kk < 2; kk++) {
            bf16x8 af[4], bfr[4];
            #pragma unroll
            for (int t = 0; t < 4; t++) {
                const int slot = ((kk * 4 + quad) ^ (l16 & 7)) * 8;
                af[t]  = *(const bf16x8*)&As[buf][(wm + t * 16 + l16) * 64 + slot];
                bfr[t] = *(const bf16x8*)&Bs[buf][(wn + t * 16 + l16) * 64 + slot];
            }
            #pragma unroll
            for (int mt = 0; mt < 4; mt++)
                #pragma unroll
                for (int nt = 0; nt < 4; nt++)
                    acc[mt][nt] = MFMA16(af[mt], bfr[nt], acc[mt][nt]);
        }
    }

    // ---- fused epilogue (no libm calls anywhere below) ----
    const int nbase = (int)n0 + wn;
    const int isQ = (nbase < 1024), isV = (nbase >= 2048);

    if (isV) {
        // V: write transposed vt[(bb*16+h)*64+d][s], s 4-consecutive per quad
        #pragma unroll
        for (int nt = 0; nt < 4; nt++) {
            const int n  = nbase + nt * 16 + l16;
            const int hv = (n - 2048) >> 6, dv = n & 63;
            const float bn = bias[n];
            #pragma unroll
            for (int mt = 0; mt < 4; mt++) {
                const int m = (int)m0 + wm + mt * 16 + quad * 4;
                const int s = m & (S_ - 1), bb = m >> 11;
                ushort4 vv;
                vv.x = f2b(acc[mt][nt][0] + bn);
                vv.y = f2b(acc[mt][nt][1] + bn);
                vv.z = f2b(acc[mt][nt][2] + bn);
                vv.w = f2b(acc[mt][nt][3] + bn);
                *(ushort4*)&vt[((size_t)(bb * H_ + hv) * HD_ + dv) * S_ + s] = vv;
            }
        }
    } else {
        unsigned short* dst = isQ ? qp : kp;
        #pragma unroll
        for (int nt = 0; nt < 4; nt++) {
            const int n  = nbase + nt * 16 + l16;
            const int nq = isQ ? n : n - 1024;
            const int h  = nq >> 6, d = nq & 63;
            const float fr = freqs[d];
            const float pb = phase_bias[h * HD_ + d];
            const float bn = bias[n];
            #pragma unroll
            for (int mt = 0; mt < 4; mt++) {
                #pragma unroll
                for (int r = 0; r < 4; r++) {
                    const int m = (int)m0 + wm + mt * 16 + quad * 4 + r;
                    const int s = m & (S_ - 1), bb = m >> 11;
                    float mu = softplus_i(acc[mt][nt][r] + bn);
                    if (isQ) mu *= SCALE_;
                    float sn, cs;
                    __sincosf((float)s * fr + pb, &sn, &cs);
                    const size_t o = ((size_t)(bb * H_ + h) * S_ + s) * 128 + d;
                    dst[o]      = f2b(mu * cs);
                    dst[o + 64] = f2b(mu * sn);
                }
            }
        }
    }
}

// ---------------------------------------------------------------------------
// MFMA flash attention: softmax1, lazy normalization, S^T trick,
// 128 q rows/block, dbuf K/V staging, causal split over grid.z.
// Exact R5/R7 structure (proven 53.6-54.6us local optimum). Failed-edit
// ledger: setprio (+1.4us), shfl-P-redistr (+9.3us), depth-2 vmcnt (+7.0us).
// ---------------------------------------------------------------------------
__global__ __launch_bounds__(512, 4) void attn_mfma_kernel(
    const unsigned short* __restrict__ qp,
    const unsigned short* __restrict__ kp,
    const unsigned short* __restrict__ vt,
    unsigned short* __restrict__ ao)
{
    __shared__ unsigned short kt_lds[2][64][128];  // [buf][key][k], chunk^=(key&15)
    __shared__ unsigned short vt_lds[2][64][64];   // [buf][d][key], chunk^=(d&7)
    __shared__ unsigned short p_lds[8][16][72];    // per-wave P: [q][key]

    const int tid = threadIdx.x;
    const int w = tid >> 6, lane = tid & 63;
    const int quad = lane >> 4, l16 = lane & 15;
    const int bh = blockIdx.y, b = bh >> 4, h = bh & 15;

    const int a = (blockIdx.z == 0) ? 15 - (int)blockIdx.x : (int)blockIdx.x;
    const int q0b = a * 128;
    const int q0 = q0b + w * 16;

    const unsigned short* qbase = qp + ((size_t)bh * S_ + q0 + l16) * 128 + quad * 8;
    bf16x8 qa[4];
    #pragma unroll
    for (int kc = 0; kc < 4; kc++) qa[kc] = *(const bf16x8*)(qbase + kc * 32);

    const int krow = lane >> 4, kslot = lane & 15;
    const int vrow = lane >> 3, vslot = lane & 7;
    const int kr0 = w * 8 + krow,     kc0 = kslot ^ (kr0 & 15);
    const int kr1 = w * 8 + 4 + krow, kc1 = kslot ^ (kr1 & 15);
    const int vd  = w * 8 + vrow,     vc  = vslot ^ (vd & 7);
    const unsigned short* kg0 = kp + ((size_t)bh * S_ + kr0) * 128 + kc0 * 8;
    const unsigned short* kg1 = kp + ((size_t)bh * S_ + kr1) * 128 + kc1 * 8;
    const unsigned short* vg0 = vt + ((size_t)bh * 64 + vd) * S_ + vc * 8;

    f32x4 o[4] = {};
    float ms = -1e30f, ls = 0.f;

    const int ntiles = 2 * a + 2;

    g2l16(kg0, &kt_lds[0][w * 8][0]);
    g2l16(kg1, &kt_lds[0][w * 8 + 4][0]);
    g2l16(vg0, &vt_lds[0][w * 8][0]);

    for (int ti = 0; ti < ntiles; ti++) {
        const int t0 = ti * 64;
        __syncthreads();
        if (ti + 1 < ntiles) {
            const int nb = (ti + 1) & 1;
            const size_t ko = (size_t)(ti + 1) * (64 * 128);
            const size_t vo = (size_t)(ti + 1) * 64;
            g2l16(kg0 + ko, &kt_lds[nb][w * 8][0]);
            g2l16(kg1 + ko, &kt_lds[nb][w * 8 + 4][0]);
            g2l16(vg0 + vo, &vt_lds[nb][w * 8][0]);
        }
        const int buf = ti & 1;

        if (t0 <= q0 + 15) {
            f32x4 sf[4];
            #pragma unroll
            for (int kg = 0; kg < 4; kg++) {
                f32x4 s = {0, 0, 0, 0};
                const int row = kg * 16 + l16;
                #pragma unroll
                for (int kc = 0; kc < 4; kc++) {
                    const int slot = (kc * 4 + quad) ^ l16;
                    s = MFMA16(*(const bf16x8*)&kt_lds[buf][row][slot * 8], qa[kc], s);
                }
                sf[kg] = s;
            }

            const int qrow = q0 + l16;
            const bool dmask = (t0 + 63 > q0);
            #pragma unroll
            for (int kg = 0; kg < 4; kg++) {
                const int kbase = t0 + kg * 16 + quad * 4;
                float v0 = sf[kg][0], v1 = sf[kg][1], v2 = sf[kg][2], v3 = sf[kg][3];
                if (dmask) {
                    v0 = (kbase     <= qrow) ? v0 : -1e30f;
                    v1 = (kbase + 1 <= qrow) ? v1 : -1e30f;
                    v2 = (kbase + 2 <= qrow) ? v2 : -1e30f;
                    v3 = (kbase + 3 <= qrow) ? v3 : -1e30f;
                }
                ms = fmaxf(ms, fmaxf(fmaxf(v0, v1), fmaxf(v2, v3)));
                const float e0 = __expf(v0), e1 = __expf(v1);
                const float e2 = __expf(v2), e3 = __expf(v3);
                ls += (e0 + e1) + (e2 + e3);
                uint2 pk;
                pk.x = pk2bf(e0, e1);
                pk.y = pk2bf(e2, e3);
                *(uint2*)&p_lds[w][l16][kg * 16 + quad * 4] = pk;
            }
            asm volatile("s_waitcnt lgkmcnt(0)" ::: "memory");
            bf16x8 pa0 = *(const bf16x8*)&p_lds[w][l16][quad * 8];
            bf16x8 pa1 = *(const bf16x8*)&p_lds[w][l16][quad * 8 + 32];

            #pragma unroll
            for (int dg = 0; dg < 4; dg++) {
                const int row = dg * 16 + l16;
                const int s0_ = quad ^ (l16 & 7);
                const int s1_ = (quad + 4) ^ (l16 & 7);
                o[dg] = MFMA16(pa0, *(const bf16x8*)&vt_lds[buf][row][s0_ * 8], o[dg]);
                o[dg] = MFMA16(pa1, *(const bf16x8*)&vt_lds[buf][row][s1_ * 8], o[dg]);
            }
        }
    }

    float mv = ms, lv = ls;
    mv = fmaxf(mv, __shfl_xor(mv, 16, 64)); lv += __shfl_xor(lv, 16, 64);
    mv = fmaxf(mv, __shfl_xor(mv, 32, 64)); lv += __shfl_xor(lv, 32, 64);
    const float inv = 1.f / (__expf(mv) + lv);

    #pragma unroll
    for (int r = 0; r < 4; r++) {
        const float ir = __shfl(inv, quad * 4 + r, 64);
        const int row = q0 + quad * 4 + r;
        const size_t base = (size_t)(b * S_ + row) * D_ + h * HD_ + l16;
        ao[base]      = f2b(o[0][r] * ir);
        ao[base + 16] = f2b(o[1][r] * ir);
        ao[base + 32] = f2b(o[2][r] * ir);
        ao[base + 48] = f2b(o[3][r] * ir);
    }
}

// ---------------------------------------------------------------------------
// Residual + LayerNorm over (ya + yb + res); residual fp32 OR bf16;
// outputs fp32 and/or bf16 (either may be null). Vectorized float4 (G13).
// Residual reads live HERE — streaming, coalesced (R8: GEMM-epilogue
// placement costs ~10us/gemm).
// ---------------------------------------------------------------------------
__global__ __launch_bounds__(256) void ln_kernel(
    const float* __restrict__ ya, const float* __restrict__ yb,
    const float* __restrict__ resF, const unsigned short* __restrict__ resB,
    const float* __restrict__ g, const float* __restrict__ beta,
    float* __restrict__ outF, unsigned short* __restrict__ outB)
{
    const int row = blockIdx.x;
    const int tid = threadIdx.x;
    const int c = tid * 4;
    const size_t base = (size_t)row * D_ + c;

    float4 t4 = *(const float4*)(ya + base);
    if (yb) {
        float4 y4 = *(const float4*)(yb + base);
        t4.x += y4.x; t4.y += y4.y; t4.z += y4.z; t4.w += y4.w;
    }
    if (resF) {
        float4 r4 = *(const float4*)(resF + base);
        t4.x += r4.x; t4.y += r4.y; t4.z += r4.z; t4.w += r4.w;
    } else if (resB) {
        ushort4 r4 = *(const ushort4*)(resB + base);
        t4.x += b2f(r4.x); t4.y += b2f(r4.y); t4.z += b2f(r4.z); t4.w += b2f(r4.w);
    }
    float sum   = (t4.x + t4.y) + (t4.z + t4.w);
    float sumsq = (t4.x * t4.x + t4.y * t4.y) + (t4.z * t4.z + t4.w * t4.w);

    #pragma unroll
    for (int off = 32; off >= 1; off >>= 1) {
        sum   += __shfl_xor(sum,   off, 64);
        sumsq += __shfl_xor(sumsq, off, 64);
    }
    __shared__ float rs_[4], rq_[4];
    int w = tid >> 6, lane = tid & 63;
    if (lane == 0) { rs_[w] = sum; rq_[w] = sumsq; }
    __syncthreads();
    float tot  = rs_[0] + rs_[1] + rs_[2] + rs_[3];
    float totq = rq_[0] + rq_[1] + rq_[2] + rq_[3];
    float mu   = tot  * (1.f / D_);
    float var  = totq * (1.f / D_) - mu * mu;
    float rstd = rsqrtf(var + 1e-5f);

    float4 g4 = *(const float4*)(g + c);
    float4 b4 = *(const float4*)(beta + c);
    float4 o4;
    o4.x = (t4.x - mu) * rstd * g4.x + b4.x;
    o4.y = (t4.y - mu) * rstd * g4.y + b4.y;
    o4.z = (t4.z - mu) * rstd * g4.z + b4.z;
    o4.w = (t4.w - mu) * rstd * g4.w + b4.w;
    if (outF) *(float4*)(outF + base) = o4;
    if (outB) {
        ushort4 ob;
        ob.x = f2b(o4.x); ob.y = f2b(o4.y); ob.z = f2b(o4.z); ob.w = f2b(o4.w);
        *(ushort4*)(outB + base) = ob;
    }
}

// ---------------------------------------------------------------------------
extern "C" void kernel_launch(void* const* d_in, const int* in_sizes, int n_in,
                              void* d_out, int out_size, void* d_ws, size_t ws_size,
                              hipStream_t stream)
{
    const float* x   = (const float*)d_in[0];
    const float* Wq  = (const float*)d_in[2];
    const float* bq  = (const float*)d_in[3];
    const float* Wk  = (const float*)d_in[4];
    const float* bk  = (const float*)d_in[5];
    const float* Wv  = (const float*)d_in[6];
    const float* bv  = (const float*)d_in[7];
    const float* Wo  = (const float*)d_in[8];
    const float* bo  = (const float*)d_in[9];
    const float* phase_bias = (const float*)d_in[10];
    const float* freqs = (const float*)d_in[11];
    const float* W1  = (const float*)d_in[12];
    const float* b1  = (const float*)d_in[13];
    const float* W2  = (const float*)d_in[14];
    const float* b2  = (const float*)d_in[15];
    const float* g1  = (const float*)d_in[16];
    const float* be1 = (const float*)d_in[17];
    const float* g2  = (const float*)d_in[18];
    const float* be2 = (const float*)d_in[19];
    float* out = (float*)d_out;

    char* base = (char*)d_ws;
    const size_t MiB = 1024 * 1024;
    unsigned short* WqkvT = (unsigned short*)(base);             // [0,6)
    unsigned short* WoT   = (unsigned short*)(base + 6  * MiB);  // [6,8)
    unsigned short* W1T   = (unsigned short*)(base + 8  * MiB);  // [8,16)
    unsigned short* W2T   = (unsigned short*)(base + 16 * MiB);  // [16,24)
    float*          bqkv  = (float*)(base + 24 * MiB);           // [24,25)
    unsigned short* xb    = (unsigned short*)(base + 25 * MiB);  // [25,33)
    unsigned short* qkvb  = (unsigned short*)(base + 33 * MiB);  // [33,57) (now unused)
    unsigned short* qpb   = (unsigned short*)(base + 57 * MiB);  // [57,73)
    unsigned short* kpb   = (unsigned short*)(base + 73 * MiB);  // [73,89)
    unsigned short* vtb   = (unsigned short*)(base + 89 * MiB);  // [89,97)
    float*          po    = (float*)(base + 89 * MiB);           // [89,121) 2 slices (vtb dead)
    unsigned short* aob   = xb;                                  // xb dead after QKV gemm
    unsigned short* x1b   = xb;                                  // aob dead after Wo gemm
    unsigned short* hb    = qkvb;                                // [33,65): qkvb region free
    float*          fo    = po;                                  // po dead after LN1

    dim3 blk(256);

    // prep: ONE fused launch (conv + bias concat + all 6 weight transposes)
    prep_kernel<<<dim3(16384), blk, 0, stream>>>(
        x, xb, bq, bk, bv, bqkv, Wq, Wk, Wv, Wo, WqkvT, WoT, W1, W1T, W2, W2T);

    // fused QKV projection + PoPE + V-transpose (writes qp, kp, vt directly)
    gemm_qkv_pope_kernel<<<dim3(3072 / 128, M_ / 128, 1), blk, 0, stream>>>(
        xb, WqkvT, bqkv, phase_bias, freqs, qpb, kpb, vtb);

    // Flash attention
    attn_mfma_kernel<<<dim3(8, B_ * H_, 2), dim3(512), 0, stream>>>(qpb, kpb, vtb, aob);

    // Output projection (split-K=2) + LN1 (bf16-only output)
    gemm_bf16_kernel<<<dim3(D_ / 128, M_ / 128, 2), blk, 0, stream>>>(
        aob, WoT, bo, po, nullptr, M_, D_ / 2, D_, D_, 0);
    ln_kernel<<<dim3(M_), blk, 0, stream>>>(
        po, po + (size_t)M_ * D_, x, nullptr, g1, be1, nullptr, x1b);

    // FFN
    gemm_bf16_kernel<<<dim3(DFF_ / 128, M_ / 128, 1), blk, 0, stream>>>(
        x1b, W1T, b1, nullptr, hb, M_, D_, D_, DFF_, 1);
    gemm_bf16_kernel<<<dim3(D_ / 128, M_ / 128, 2), blk, 0, stream>>>(
        hb, W2T, b2, fo, nullptr, M_, DFF_ / 2, DFF_, D_, 0);
    ln_kernel<<<dim3(M_), blk, 0, stream>>>(
        fo, fo + (size_t)M_ * D_, nullptr, x1b, g2, be2, out, nullptr);
}

// Round 11
// 352.658 us; speedup vs baseline: 1.1607x; 1.0378x over previous
//
#include <hip/hip_runtime.h>
#include <hip/hip_bf16.h>
#include <math.h>

#define B_   2
#define S_   2048
#define D_   1024
#define H_   16
#define HD_  64
#define DFF_ 4096
#define M_   (B_*S_)   // 4096 rows
#define SCALE_ 0.08838834764831845f  // 1/sqrt(128)

typedef __attribute__((ext_vector_type(8))) short bf16x8;
typedef __attribute__((ext_vector_type(4))) float f32x4;

#define MFMA16(a,b,c) __builtin_amdgcn_mfma_f32_16x16x32_bf16((a),(b),(c),0,0,0)

__device__ __forceinline__ unsigned short f2b(float f) {
    union { float f; unsigned u; } v; v.f = f;
    return (unsigned short)((v.u + 0x7FFFu + ((v.u >> 16) & 1u)) >> 16);
}
__device__ __forceinline__ float b2f(unsigned short s) {
    union { unsigned u; float f; } v; v.u = ((unsigned)s) << 16;
    return v.f;
}
// pack two f32 -> two bf16 (truncating) in ONE v_perm_b32
__device__ __forceinline__ unsigned pk2bf(float a, float b) {
    union { float f; unsigned u; } ua, ub; ua.f = a; ub.f = b;
    return __builtin_amdgcn_perm(ub.u, ua.u, 0x07060302u);
}
__device__ __forceinline__ float softplus_f(float x) {
    return fmaxf(x, 0.f) + log1pf(__expf(-fabsf(x)));
}
// ALL-INLINE softplus for use inside MFMA kernels (R2 lesson: libm calls
// (sincosf/log1pf) clobber VGPRs -> acc spills -> 1GB scratch, 8x slowdown).
// __logf/__expf are inline v_log/v_exp; err ~1e-6 << bf16 rounding.
__device__ __forceinline__ float softplus_i(float x) {
    return fmaxf(x, 0.f) + __logf(1.f + __expf(-fabsf(x)));
}
// async global->LDS, 16B per lane. LDS dest = base + lane*16 (wave-uniform base).
__device__ __forceinline__ void g2l16(const void* g, void* l) {
    __builtin_amdgcn_global_load_lds(
        (const __attribute__((address_space(1))) unsigned int*)g,
        (__attribute__((address_space(3))) unsigned int*)l, 16, 0, 0);
}

// ---------------------------------------------------------------------------
// Fused prep: ONE launch for x->bf16 conv (+bias concat), the 4 square
// weight transposes, W1T and W2T. All independent; block ranges:
//   [0,4096)       conv (+bqkv build in blocks 0..11)
//   [4096,8192)    wtrans4 (Wq/Wk/Wv/Wo, 1024 blocks each)
//   [8192,12288)   W1T: K=1024, N=4096
//   [12288,16384)  W2T: K=4096, N=1024
// ---------------------------------------------------------------------------
__global__ __launch_bounds__(256) void prep_kernel(
    const float* __restrict__ x, unsigned short* __restrict__ xb,
    const float* __restrict__ bq, const float* __restrict__ bk,
    const float* __restrict__ bv, float* __restrict__ bqkv,
    const float* __restrict__ Wq, const float* __restrict__ Wk,
    const float* __restrict__ Wv, const float* __restrict__ Wo,
    unsigned short* __restrict__ WqkvT, unsigned short* __restrict__ WoT,
    const float* __restrict__ W1, unsigned short* __restrict__ W1T,
    const float* __restrict__ W2, unsigned short* __restrict__ W2T)
{
    __shared__ float tile[32][33];
    const int bid = blockIdx.x;
    const int tid = threadIdx.x;

    if (bid < 4096) {
        // ---- conv + bias concat ----
        int i = (bid * 256 + tid) * 4;
        float4 v = *(const float4*)&x[i];
        ushort4 o;
        o.x = f2b(v.x); o.y = f2b(v.y); o.z = f2b(v.z); o.w = f2b(v.w);
        *(ushort4*)&xb[i] = o;
        int j = bid * 256 + tid;
        if (j < 3072)
            bqkv[j] = (j < 1024) ? bq[j] : (j < 2048 ? bk[j - 1024] : bv[j - 2048]);
        return;
    }

    // ---- transposes: pick source/dest and geometry ----
    const float* W; unsigned short* WT; int K, N, bx, by;
    if (bid < 8192) {
        const int idx = bid - 4096;           // 0..4095
        const int z = idx >> 10;              // 0..3
        W  = (z == 0) ? Wq : (z == 1) ? Wk : (z == 2) ? Wv : Wo;
        WT = (z < 3) ? WqkvT + (size_t)z * 1024 * 1024 : WoT;
        K = 1024; N = 1024;
        bx = idx & 31; by = (idx >> 5) & 31;
    } else if (bid < 12288) {
        const int idx = bid - 8192;           // 0..4095
        W = W1; WT = W1T; K = 1024; N = 4096;
        bx = idx & 127; by = idx >> 7;
    } else {
        const int idx = bid - 12288;          // 0..4095
        W = W2; WT = W2T; K = 4096; N = 1024;
        bx = idx & 31; by = idx >> 5;
    }
    const int n0 = bx * 32, k0 = by * 32;
    const int tx = tid & 31, ty = tid >> 5;   // ty 0..7
    #pragma unroll
    for (int i = 0; i < 4; i++)
        tile[ty + 8*i][tx] = W[(size_t)(k0 + ty + 8*i) * N + n0 + tx];
    __syncthreads();
    #pragma unroll
    for (int i = 0; i < 4; i++)
        WT[(size_t)(n0 + ty + 8*i) * K + k0 + tx] = f2b(tile[tx][ty + 8*i]);
}

// ---------------------------------------------------------------------------
// bf16 GEMM, 128^2 tile, BK=64, XOR-swizzled LDS, double-buffered staging,
// XCD-aware remap, optional split-K. C[M,N]=A[M,lda]@WT[N,lda]^T (+bias z=0).
// Epilogue kept CLEAN (R8: epilogue loads serialize against store drain).
// ---------------------------------------------------------------------------
__global__ __launch_bounds__(256) void gemm_bf16_kernel(
    const unsigned short* __restrict__ A,
    const unsigned short* __restrict__ WT,
    const float* __restrict__ bias,
    float* __restrict__ outF, unsigned short* __restrict__ outB,
    int M, int Kslice, int lda, int N, int relu)
{
    __shared__ unsigned short As[2][128 * 64];
    __shared__ unsigned short Bs[2][128 * 64];

    const int tid = threadIdx.x;
    const int w = tid >> 6, lane = tid & 63;
    const int quad = lane >> 4, l16 = lane & 15;

    const int nn = gridDim.x, nm = gridDim.y;
    const int lin = ((int)blockIdx.z * nm + (int)blockIdx.y) * nn + (int)blockIdx.x;
    const int per = (nn * nm * (int)gridDim.z) >> 3;
    const int id  = (lin & 7) * per + (lin >> 3);
    const int zz  = id / (nn * nm);
    const int rem = id - zz * nn * nm;
    const int mt_ = rem / nn, nt_ = rem - mt_ * nn;

    const size_t m0 = (size_t)mt_ * 128, n0 = (size_t)nt_ * 128;
    const int wm = (w >> 1) * 64, wn = (w & 1) * 64;
    const int koff = zz * Kslice;

    const int srow = lane >> 3;                       // 0..7 row within group
    const int sc   = ((lane & 7) ^ srow) * 8;         // swizzled global chunk
    const unsigned short* ga = A  + (m0 + w * 32 + srow) * (size_t)lda + koff + sc;
    const unsigned short* gb = WT + (n0 + w * 32 + srow) * (size_t)lda + koff + sc;
    const size_t rows8 = (size_t)8 * lda;

    f32x4 acc[4][4] = {};
    const int niter = Kslice >> 6;

    #pragma unroll
    for (int j = 0; j < 4; j++) g2l16(ga + j * rows8, &As[0][(w * 32 + j * 8) * 64]);
    #pragma unroll
    for (int j = 0; j < 4; j++) g2l16(gb + j * rows8, &Bs[0][(w * 32 + j * 8) * 64]);

    for (int i = 0; i < niter; i++) {
        __syncthreads();
        if (i + 1 < niter) {
            const int nb = (i + 1) & 1, k0 = (i + 1) << 6;
            #pragma unroll
            for (int j = 0; j < 4; j++)
                g2l16(ga + j * rows8 + k0, &As[nb][(w * 32 + j * 8) * 64]);
            #pragma unroll
            for (int j = 0; j < 4; j++)
                g2l16(gb + j * rows8 + k0, &Bs[nb][(w * 32 + j * 8) * 64]);
        }
        const int buf = i & 1;

        #pragma unroll
        for (int kk = 0; kk < 2; kk++) {
            bf16x8 af[4], bfr[4];
            #pragma unroll
            for (int t = 0; t < 4; t++) {
                const int slot = ((kk * 4 + quad) ^ (l16 & 7)) * 8;
                af[t]  = *(const bf16x8*)&As[buf][(wm + t * 16 + l16) * 64 + slot];
                bfr[t] = *(const bf16x8*)&Bs[buf][(wn + t * 16 + l16) * 64 + slot];
            }
            #pragma unroll
            for (int mt = 0; mt < 4; mt++)
                #pragma unroll
                for (int nt = 0; nt < 4; nt++)
                    acc[mt][nt] = MFMA16(af[mt], bfr[nt], acc[mt][nt]);
        }
    }

    float bv[4];
    #pragma unroll
    for (int nt = 0; nt < 4; nt++)
        bv[nt] = (zz == 0) ? bias[n0 + wn + nt * 16 + l16] : 0.f;

    float* outFz = outF ? outF + (size_t)zz * M * N : nullptr;

    #pragma unroll
    for (int mt = 0; mt < 4; mt++) {
        #pragma unroll
        for (int nt = 0; nt < 4; nt++) {
            const size_t n = n0 + wn + nt * 16 + l16;
            #pragma unroll
            for (int r = 0; r < 4; r++) {
                const size_t m = m0 + wm + mt * 16 + quad * 4 + r;
                float val = acc[mt][nt][r] + bv[nt];
                if (relu) val = fmaxf(val, 0.f);
                const size_t idx = m * N + n;
                if (outFz) outFz[idx] = val;
                if (outB) outB[idx] = f2b(val);
            }
        }
    }
}

// ---------------------------------------------------------------------------
// QKV GEMM + fused PoPE + fused V-transpose epilogue (R11: LDS-staged,
// coalesced). Same 128^2 main loop; smem reused after the K-loop to stage
// the output tile, then written out as full 256B row segments (16B/lane):
//  - q/k tile covers 2 heads x all 64 d -> COMPLETE qp/kp rows
//    [cos d 0..63 | sin d 0..63]; 16 global stores/thread vs 128 scalars.
//  - v tile covers 2 heads x 64 d-rows x 128 s -> 256B segments of vt rows.
// R10 counters showed the scattered epilogue cost: FETCH 59MB (partial-line
// RMW, vs ~37MB plain GEMM), WRITE 58.5MB (vs 40 ideal), 128 store instrs.
// LDS staging is XOR-swizzled (quad*16 ^ r*8 for q/k; (d&15)<<3 for v) to
// keep both write and read phases low-conflict. No libm calls (R2 lesson).
// ---------------------------------------------------------------------------
__global__ __launch_bounds__(256) void gemm_qkv_pope_kernel(
    const unsigned short* __restrict__ A,
    const unsigned short* __restrict__ WT,
    const float* __restrict__ bias,
    const float* __restrict__ phase_bias, const float* __restrict__ freqs,
    unsigned short* __restrict__ qp, unsigned short* __restrict__ kp,
    unsigned short* __restrict__ vt)
{
    __shared__ unsigned short smem[4][128 * 64];   // As = smem[0..1], Bs = smem[2..3]

    const int tid = threadIdx.x;
    const int w = tid >> 6, lane = tid & 63;
    const int quad = lane >> 4, l16 = lane & 15;

    const int nn = gridDim.x, nm = gridDim.y;   // 24 x 32
    const int lin = (int)blockIdx.y * nn + (int)blockIdx.x;
    const int per = (nn * nm) >> 3;
    const int id  = (lin & 7) * per + (lin >> 3);
    const int mt_ = id / nn, nt_ = id - mt_ * nn;

    const size_t m0 = (size_t)mt_ * 128, n0 = (size_t)nt_ * 128;
    const int wm = (w >> 1) * 64, wn = (w & 1) * 64;

    const int srow = lane >> 3;
    const int sc   = ((lane & 7) ^ srow) * 8;
    const unsigned short* ga = A  + (m0 + w * 32 + srow) * (size_t)D_ + sc;
    const unsigned short* gb = WT + (n0 + w * 32 + srow) * (size_t)D_ + sc;
    const size_t rows8 = (size_t)8 * D_;

    f32x4 acc[4][4] = {};
    const int niter = D_ >> 6;   // 16

    #pragma unroll
    for (int j = 0; j < 4; j++) g2l16(ga + j * rows8, &smem[0][(w * 32 + j * 8) * 64]);
    #pragma unroll
    for (int j = 0; j < 4; j++) g2l16(gb + j * rows8, &smem[2][(w * 32 + j * 8) * 64]);

    for (int i = 0; i < niter; i++) {
        __syncthreads();
        if (i + 1 < niter) {
            const int nb = (i + 1) & 1, k0 = (i + 1) << 6;
            #pragma unroll
            for (int j = 0; j < 4; j++)
                g2l16(ga + j * rows8 + k0, &smem[nb][(w * 32 + j * 8) * 64]);
            #pragma unroll
            for (int j = 0; j < 4; j++)
                g2l16(gb + j * rows8 + k0, &smem[2 + nb][(w * 32 + j * 8) * 64]);
        }
        const int buf = i & 1;

        #pragma unroll
        for (int kk = 0; kk < 2; kk++) {
            bf16x8 af[4], bfr[4];
            #pragma unroll
            for (int t = 0; t < 4; t++) {
                const int slot = ((kk * 4 + quad) ^ (l16 & 7)) * 8;
                af[t]  = *(const bf16x8*)&smem[buf][(wm + t * 16 + l16) * 64 + slot];
                bfr[t] = *(const bf16x8*)&smem[2 + buf][(wn + t * 16 + l16) * 64 + slot];
            }
            #pragma unroll
            for (int mt = 0; mt < 4; mt++)
                #pragma unroll
                for (int nt = 0; nt < 4; nt++)
                    acc[mt][nt] = MFMA16(af[mt], bfr[nt], acc[mt][nt]);
        }
    }

    // ---- LDS-staged epilogue (no libm calls) ----
    __syncthreads();                       // all waves done with K-loop LDS
    unsigned short* eld = &smem[0][0];     // 64KB flat

    const int nbase = (int)n0;
    const int isQ = (nbase < 1024), isV = (nbase >= 2048);
    const int bb  = (int)(m0 >> 11);
    const int s_base = (int)(m0 & (S_ - 1));

    if (isV) {
        const int hv0 = (nbase - 2048) >> 6;
        // stage: eld[d_row 0..127][s 0..127], s XOR-swizzled by (d_row&15)<<3
        #pragma unroll
        for (int nt = 0; nt < 4; nt++) {
            const int dr = wn + nt * 16 + l16;           // 0..127
            const float bn = bias[nbase + dr];
            #pragma unroll
            for (int mt = 0; mt < 4; mt++) {
                const int sl = wm + mt * 16 + quad * 4;
                ushort4 vv;
                vv.x = f2b(acc[mt][nt][0] + bn);
                vv.y = f2b(acc[mt][nt][1] + bn);
                vv.z = f2b(acc[mt][nt][2] + bn);
                vv.w = f2b(acc[mt][nt][3] + bn);
                *(ushort4*)&eld[dr * 128 + (sl ^ ((dr & 15) << 3))] = vv;
            }
        }
        __syncthreads();
        // write out: 128 rows x 256B, 16 rows/iter (16 threads x 16B each)
        for (int j = 0; j < 8; j++) {
            const int r2 = j * 16 + (tid >> 4);          // 0..127
            const int sb = (tid & 15) * 8;
            uint4 v = *(const uint4*)&eld[r2 * 128 + (sb ^ ((r2 & 15) << 3))];
            *(uint4*)&vt[((size_t)(bb * H_ + hv0) * HD_ + r2) * S_ + s_base + sb] = v;
        }
    } else {
        const int nq0 = isQ ? nbase : nbase - 1024;
        const int h0 = nq0 >> 6;
        unsigned short* dst = isQ ? qp : kp;
        // stage: eld[ml 0..127][256] = [hl][cos d | sin d], d XOR (quad*16 ^ r*8)
        #pragma unroll
        for (int nt = 0; nt < 4; nt++) {
            const int nl = wn + nt * 16 + l16;           // 0..127
            const int hl = nl >> 6, d = nl & 63;
            const float fr = freqs[d];
            const float pb = phase_bias[(h0 + hl) * HD_ + d];
            const float bn = bias[nbase + nl];
            #pragma unroll
            for (int mt = 0; mt < 4; mt++) {
                #pragma unroll
                for (int r = 0; r < 4; r++) {
                    const int ml = wm + mt * 16 + quad * 4 + r;
                    const int s = s_base + ml;
                    float mu = softplus_i(acc[mt][nt][r] + bn);
                    if (isQ) mu *= SCALE_;
                    float sn, cs;
                    __sincosf((float)s * fr + pb, &sn, &cs);
                    const int dd = d ^ (quad * 16) ^ (r * 8);
                    const int rb = ml * 256 + hl * 128;
                    eld[rb + dd]      = f2b(mu * cs);
                    eld[rb + 64 + dd] = f2b(mu * sn);
                }
            }
        }
        __syncthreads();
        // write out: 256 rows (2 hl x 128 ml) x 256B, 16 rows/iter
        for (int j = 0; j < 16; j++) {
            const int rr = j * 16 + (tid >> 4);          // 0..255
            const int hl = rr >> 7, ml = rr & 127;
            const int eb = (tid & 15) * 8;               // 0..120
            const int q64 = eb >> 6, wv = eb & 63;
            const int sw = (((ml >> 2) & 3) * 16) ^ ((ml & 3) * 8);
            uint4 v = *(const uint4*)&eld[ml * 256 + hl * 128 + q64 * 64 + (wv ^ sw)];
            *(uint4*)&dst[((size_t)(bb * H_ + h0 + hl) * S_ + s_base + ml) * 128 + eb] = v;
        }
    }
}

// ---------------------------------------------------------------------------
// MFMA flash attention: softmax1, lazy normalization, S^T trick,
// 128 q rows/block, dbuf K/V staging, causal split over grid.z.
// Exact R5/R7 structure (proven 53.6-54.6us local optimum). Failed-edit
// ledger: setprio (+1.4us), shfl-P-redistr (+9.3us), depth-2 vmcnt (+7.0us).
// ---------------------------------------------------------------------------
__global__ __launch_bounds__(512, 4) void attn_mfma_kernel(
    const unsigned short* __restrict__ qp,
    const unsigned short* __restrict__ kp,
    const unsigned short* __restrict__ vt,
    unsigned short* __restrict__ ao)
{
    __shared__ unsigned short kt_lds[2][64][128];  // [buf][key][k], chunk^=(key&15)
    __shared__ unsigned short vt_lds[2][64][64];   // [buf][d][key], chunk^=(d&7)
    __shared__ unsigned short p_lds[8][16][72];    // per-wave P: [q][key]

    const int tid = threadIdx.x;
    const int w = tid >> 6, lane = tid & 63;
    const int quad = lane >> 4, l16 = lane & 15;
    const int bh = blockIdx.y, b = bh >> 4, h = bh & 15;

    const int a = (blockIdx.z == 0) ? 15 - (int)blockIdx.x : (int)blockIdx.x;
    const int q0b = a * 128;
    const int q0 = q0b + w * 16;

    const unsigned short* qbase = qp + ((size_t)bh * S_ + q0 + l16) * 128 + quad * 8;
    bf16x8 qa[4];
    #pragma unroll
    for (int kc = 0; kc < 4; kc++) qa[kc] = *(const bf16x8*)(qbase + kc * 32);

    const int krow = lane >> 4, kslot = lane & 15;
    const int vrow = lane >> 3, vslot = lane & 7;
    const int kr0 = w * 8 + krow,     kc0 = kslot ^ (kr0 & 15);
    const int kr1 = w * 8 + 4 + krow, kc1 = kslot ^ (kr1 & 15);
    const int vd  = w * 8 + vrow,     vc  = vslot ^ (vd & 7);
    const unsigned short* kg0 = kp + ((size_t)bh * S_ + kr0) * 128 + kc0 * 8;
    const unsigned short* kg1 = kp + ((size_t)bh * S_ + kr1) * 128 + kc1 * 8;
    const unsigned short* vg0 = vt + ((size_t)bh * 64 + vd) * S_ + vc * 8;

    f32x4 o[4] = {};
    float ms = -1e30f, ls = 0.f;

    const int ntiles = 2 * a + 2;

    g2l16(kg0, &kt_lds[0][w * 8][0]);
    g2l16(kg1, &kt_lds[0][w * 8 + 4][0]);
    g2l16(vg0, &vt_lds[0][w * 8][0]);

    for (int ti = 0; ti < ntiles; ti++) {
        const int t0 = ti * 64;
        __syncthreads();
        if (ti + 1 < ntiles) {
            const int nb = (ti + 1) & 1;
            const size_t ko = (size_t)(ti + 1) * (64 * 128);
            const size_t vo = (size_t)(ti + 1) * 64;
            g2l16(kg0 + ko, &kt_lds[nb][w * 8][0]);
            g2l16(kg1 + ko, &kt_lds[nb][w * 8 + 4][0]);
            g2l16(vg0 + vo, &vt_lds[nb][w * 8][0]);
        }
        const int buf = ti & 1;

        if (t0 <= q0 + 15) {
            f32x4 sf[4];
            #pragma unroll
            for (int kg = 0; kg < 4; kg++) {
                f32x4 s = {0, 0, 0, 0};
                const int row = kg * 16 + l16;
                #pragma unroll
                for (int kc = 0; kc < 4; kc++) {
                    const int slot = (kc * 4 + quad) ^ l16;
                    s = MFMA16(*(const bf16x8*)&kt_lds[buf][row][slot * 8], qa[kc], s);
                }
                sf[kg] = s;
            }

            const int qrow = q0 + l16;
            const bool dmask = (t0 + 63 > q0);
            #pragma unroll
            for (int kg = 0; kg < 4; kg++) {
                const int kbase = t0 + kg * 16 + quad * 4;
                float v0 = sf[kg][0], v1 = sf[kg][1], v2 = sf[kg][2], v3 = sf[kg][3];
                if (dmask) {
                    v0 = (kbase     <= qrow) ? v0 : -1e30f;
                    v1 = (kbase + 1 <= qrow) ? v1 : -1e30f;
                    v2 = (kbase + 2 <= qrow) ? v2 : -1e30f;
                    v3 = (kbase + 3 <= qrow) ? v3 : -1e30f;
                }
                ms = fmaxf(ms, fmaxf(fmaxf(v0, v1), fmaxf(v2, v3)));
                const float e0 = __expf(v0), e1 = __expf(v1);
                const float e2 = __expf(v2), e3 = __expf(v3);
                ls += (e0 + e1) + (e2 + e3);
                uint2 pk;
                pk.x = pk2bf(e0, e1);
                pk.y = pk2bf(e2, e3);
                *(uint2*)&p_lds[w][l16][kg * 16 + quad * 4] = pk;
            }
            asm volatile("s_waitcnt lgkmcnt(0)" ::: "memory");
            bf16x8 pa0 = *(const bf16x8*)&p_lds[w][l16][quad * 8];
            bf16x8 pa1 = *(const bf16x8*)&p_lds[w][l16][quad * 8 + 32];

            #pragma unroll
            for (int dg = 0; dg < 4; dg++) {
                const int row = dg * 16 + l16;
                const int s0_ = quad ^ (l16 & 7);
                const int s1_ = (quad + 4) ^ (l16 & 7);
                o[dg] = MFMA16(pa0, *(const bf16x8*)&vt_lds[buf][row][s0_ * 8], o[dg]);
                o[dg] = MFMA16(pa1, *(const bf16x8*)&vt_lds[buf][row][s1_ * 8], o[dg]);
            }
        }
    }

    float mv = ms, lv = ls;
    mv = fmaxf(mv, __shfl_xor(mv, 16, 64)); lv += __shfl_xor(lv, 16, 64);
    mv = fmaxf(mv, __shfl_xor(mv, 32, 64)); lv += __shfl_xor(lv, 32, 64);
    const float inv = 1.f / (__expf(mv) + lv);

    #pragma unroll
    for (int r = 0; r < 4; r++) {
        const float ir = __shfl(inv, quad * 4 + r, 64);
        const int row = q0 + quad * 4 + r;
        const size_t base = (size_t)(b * S_ + row) * D_ + h * HD_ + l16;
        ao[base]      = f2b(o[0][r] * ir);
        ao[base + 16] = f2b(o[1][r] * ir);
        ao[base + 32] = f2b(o[2][r] * ir);
        ao[base + 48] = f2b(o[3][r] * ir);
    }
}

// ---------------------------------------------------------------------------
// Residual + LayerNorm over (ya + yb + res); residual fp32 OR bf16;
// outputs fp32 and/or bf16 (either may be null). Vectorized float4 (G13).
// Residual reads live HERE — streaming, coalesced (R8: GEMM-epilogue
// placement costs ~10us/gemm).
// ---------------------------------------------------------------------------
__global__ __launch_bounds__(256) void ln_kernel(
    const float* __restrict__ ya, const float* __restrict__ yb,
    const float* __restrict__ resF, const unsigned short* __restrict__ resB,
    const float* __restrict__ g, const float* __restrict__ beta,
    float* __restrict__ outF, unsigned short* __restrict__ outB)
{
    const int row = blockIdx.x;
    const int tid = threadIdx.x;
    const int c = tid * 4;
    const size_t base = (size_t)row * D_ + c;

    float4 t4 = *(const float4*)(ya + base);
    if (yb) {
        float4 y4 = *(const float4*)(yb + base);
        t4.x += y4.x; t4.y += y4.y; t4.z += y4.z; t4.w += y4.w;
    }
    if (resF) {
        float4 r4 = *(const float4*)(resF + base);
        t4.x += r4.x; t4.y += r4.y; t4.z += r4.z; t4.w += r4.w;
    } else if (resB) {
        ushort4 r4 = *(const ushort4*)(resB + base);
        t4.x += b2f(r4.x); t4.y += b2f(r4.y); t4.z += b2f(r4.z); t4.w += b2f(r4.w);
    }
    float sum   = (t4.x + t4.y) + (t4.z + t4.w);
    float sumsq = (t4.x * t4.x + t4.y * t4.y) + (t4.z * t4.z + t4.w * t4.w);

    #pragma unroll
    for (int off = 32; off >= 1; off >>= 1) {
        sum   += __shfl_xor(sum,   off, 64);
        sumsq += __shfl_xor(sumsq, off, 64);
    }
    __shared__ float rs_[4], rq_[4];
    int w = tid >> 6, lane = tid & 63;
    if (lane == 0) { rs_[w] = sum; rq_[w] = sumsq; }
    __syncthreads();
    float tot  = rs_[0] + rs_[1] + rs_[2] + rs_[3];
    float totq = rq_[0] + rq_[1] + rq_[2] + rq_[3];
    float mu   = tot  * (1.f / D_);
    float var  = totq * (1.f / D_) - mu * mu;
    float rstd = rsqrtf(var + 1e-5f);

    float4 g4 = *(const float4*)(g + c);
    float4 b4 = *(const float4*)(beta + c);
    float4 o4;
    o4.x = (t4.x - mu) * rstd * g4.x + b4.x;
    o4.y = (t4.y - mu) * rstd * g4.y + b4.y;
    o4.z = (t4.z - mu) * rstd * g4.z + b4.z;
    o4.w = (t4.w - mu) * rstd * g4.w + b4.w;
    if (outF) *(float4*)(outF + base) = o4;
    if (outB) {
        ushort4 ob;
        ob.x = f2b(o4.x); ob.y = f2b(o4.y); ob.z = f2b(o4.z); ob.w = f2b(o4.w);
        *(ushort4*)(outB + base) = ob;
    }
}

// ---------------------------------------------------------------------------
extern "C" void kernel_launch(void* const* d_in, const int* in_sizes, int n_in,
                              void* d_out, int out_size, void* d_ws, size_t ws_size,
                              hipStream_t stream)
{
    const float* x   = (const float*)d_in[0];
    const float* Wq  = (const float*)d_in[2];
    const float* bq  = (const float*)d_in[3];
    const float* Wk  = (const float*)d_in[4];
    const float* bk  = (const float*)d_in[5];
    const float* Wv  = (const float*)d_in[6];
    const float* bv  = (const float*)d_in[7];
    const float* Wo  = (const float*)d_in[8];
    const float* bo  = (const float*)d_in[9];
    const float* phase_bias = (const float*)d_in[10];
    const float* freqs = (const float*)d_in[11];
    const float* W1  = (const float*)d_in[12];
    const float* b1  = (const float*)d_in[13];
    const float* W2  = (const float*)d_in[14];
    const float* b2  = (const float*)d_in[15];
    const float* g1  = (const float*)d_in[16];
    const float* be1 = (const float*)d_in[17];
    const float* g2  = (const float*)d_in[18];
    const float* be2 = (const float*)d_in[19];
    float* out = (float*)d_out;

    char* base = (char*)d_ws;
    const size_t MiB = 1024 * 1024;
    unsigned short* WqkvT = (unsigned short*)(base);             // [0,6)
    unsigned short* WoT   = (unsigned short*)(base + 6  * MiB);  // [6,8)
    unsigned short* W1T   = (unsigned short*)(base + 8  * MiB);  // [8,16)
    unsigned short* W2T   = (unsigned short*)(base + 16 * MiB);  // [16,24)
    float*          bqkv  = (float*)(base + 24 * MiB);           // [24,25)
    unsigned short* xb    = (unsigned short*)(base + 25 * MiB);  // [25,33)
    unsigned short* qkvb  = (unsigned short*)(base + 33 * MiB);  // [33,57) (free)
    unsigned short* qpb   = (unsigned short*)(base + 57 * MiB);  // [57,73)
    unsigned short* kpb   = (unsigned short*)(base + 73 * MiB);  // [73,89)
    unsigned short* vtb   = (unsigned short*)(base + 89 * MiB);  // [89,97)
    float*          po    = (float*)(base + 89 * MiB);           // [89,121) 2 slices (vtb dead)
    unsigned short* aob   = xb;                                  // xb dead after QKV gemm
    unsigned short* x1b   = xb;                                  // aob dead after Wo gemm
    unsigned short* hb    = qkvb;                                // [33,65): qkvb region free
    float*          fo    = po;                                  // po dead after LN1

    dim3 blk(256);

    // prep: ONE fused launch (conv + bias concat + all 6 weight transposes)
    prep_kernel<<<dim3(16384), blk, 0, stream>>>(
        x, xb, bq, bk, bv, bqkv, Wq, Wk, Wv, Wo, WqkvT, WoT, W1, W1T, W2, W2T);

    // fused QKV projection + PoPE + V-transpose (writes qp, kp, vt directly)
    gemm_qkv_pope_kernel<<<dim3(3072 / 128, M_ / 128, 1), blk, 0, stream>>>(
        xb, WqkvT, bqkv, phase_bias, freqs, qpb, kpb, vtb);

    // Flash attention
    attn_mfma_kernel<<<dim3(8, B_ * H_, 2), dim3(512), 0, stream>>>(qpb, kpb, vtb, aob);

    // Output projection (split-K=2) + LN1 (bf16-only output)
    gemm_bf16_kernel<<<dim3(D_ / 128, M_ / 128, 2), blk, 0, stream>>>(
        aob, WoT, bo, po, nullptr, M_, D_ / 2, D_, D_, 0);
    ln_kernel<<<dim3(M_), blk, 0, stream>>>(
        po, po + (size_t)M_ * D_, x, nullptr, g1, be1, nullptr, x1b);

    // FFN
    gemm_bf16_kernel<<<dim3(DFF_ / 128, M_ / 128, 1), blk, 0, stream>>>(
        x1b, W1T, b1, nullptr, hb, M_, D_, D_, DFF_, 1);
    gemm_bf16_kernel<<<dim3(D_ / 128, M_ / 128, 2), blk, 0, stream>>>(
        hb, W2T, b2, fo, nullptr, M_, DFF_ / 2, DFF_, D_, 0);
    ln_kernel<<<dim3(M_), blk, 0, stream>>>(
        fo, fo + (size_t)M_ * D_, nullptr, x1b, g2, be2, out, nullptr);
}